// Round 1
// baseline (449.384 us; speedup 1.0000x reference)
//
#include <hip/hip_runtime.h>

#define NNODES 6
#define CDIM 256
#define NPAIR 15
#define BTOT 8192

// offsets in d_out (floats)
#define OUT0_OFF 0
#define XN_OFF   49152ULL          // 8192*6
#define WL_OFF   12632064ULL       // 49152 + 8192*256*6

static __device__ __forceinline__ float tanh5(float v) {
#pragma unroll
  for (int t = 0; t < 5; ++t) {
    float e = __expf(2.0f * v);
    v = 1.0f - __fdividef(2.0f, e + 1.0f);
  }
  return v;
}

__global__ void transpose_k1(const float* __restrict__ K1, float* __restrict__ K1T) {
  int t = blockIdx.x * 256 + threadIdx.x;
  int o = t >> 8, c = t & 255;
  K1T[c * 256 + o] = K1[t];
}

template <bool USET>
__global__ __launch_bounds__(256) void pdegcn_main(
    const float* __restrict__ x,
    const float* __restrict__ K1,
    const float* __restrict__ K1T,
    const float* __restrict__ KNc,
    const float* __restrict__ alphap,
    const float* __restrict__ hp,
    float* __restrict__ out)
{
  __shared__ float xs[4][NNODES * CDIM];   // per-wave x_b staging (24 KiB)
  __shared__ float kt[16 * CDIM];          // shared K1T tile (16 KiB)
  __shared__ float Ms[4][36];              // per-wave final 6x6 out tile

  const int wv = threadIdx.x >> 6;
  const int lane = threadIdx.x & 63;
  const int b = blockIdx.x * 4 + wv;
  const int c0 = lane * 4;

  const float alpha = alphap[0];
  const float h = hp[0];
  const float beta = 1.0f / (1.0f + __expf(-alpha));
  const float al = (1.0f - beta) / h;
  const float be = beta / (h * h);
  const float invd = 1.0f / (be + al);
  const float cA = (2.0f * be + al) * invd;
  const float cB = -be * invd;

  // ---- stage x_b into LDS ----
  {
    const float4* src = reinterpret_cast<const float4*>(x + (size_t)b * (NNODES * CDIM));
    float4* dst = reinterpret_cast<float4*>(xs[wv]);
#pragma unroll
    for (int i = 0; i < 6; ++i) dst[lane + 64 * i] = src[lane + 64 * i];
  }
  __syncthreads();

  // ---- phase 1: xn0[o,n] = relu(sum_c K1[o,c] * x[b,n,c]); lane owns o in [c0,c0+4) ----
  float acc[4][6];
#pragma unroll
  for (int k = 0; k < 4; ++k)
#pragma unroll
    for (int n = 0; n < 6; ++n) acc[k][n] = 0.0f;

  if (USET) {
#pragma unroll 1
    for (int ct = 0; ct < CDIM; ct += 16) {
      // stage K1T rows [ct, ct+16) into LDS, shared by the 4 waves
      const float4* src = reinterpret_cast<const float4*>(K1T + (size_t)ct * CDIM);
      float4* dstk = reinterpret_cast<float4*>(kt);
#pragma unroll
      for (int i = 0; i < 4; ++i) dstk[threadIdx.x + 256 * i] = src[threadIdx.x + 256 * i];
      __syncthreads();
#pragma unroll
      for (int c = 0; c < 16; c += 4) {
        float xr[6][4];
#pragma unroll
        for (int n = 0; n < 6; ++n) {
          float4 v = *reinterpret_cast<const float4*>(&xs[wv][n * CDIM + ct + c]);
          xr[n][0] = v.x; xr[n][1] = v.y; xr[n][2] = v.z; xr[n][3] = v.w;
        }
#pragma unroll
        for (int cc = 0; cc < 4; ++cc) {
          float4 kv = *reinterpret_cast<const float4*>(&kt[(c + cc) * CDIM + c0]);
          float kk[4] = {kv.x, kv.y, kv.z, kv.w};
#pragma unroll
          for (int k = 0; k < 4; ++k)
#pragma unroll
            for (int n = 0; n < 6; ++n)
              acc[k][n] = fmaf(kk[k], xr[n][cc], acc[k][n]);
        }
      }
      __syncthreads();
    }
  } else {
    // fallback: direct (uncoalesced) K1 reads, correctness path if ws too small
#pragma unroll 1
    for (int c = 0; c < CDIM; c += 4) {
      float xr[6][4];
#pragma unroll
      for (int n = 0; n < 6; ++n) {
        float4 v = *reinterpret_cast<const float4*>(&xs[wv][n * CDIM + c]);
        xr[n][0] = v.x; xr[n][1] = v.y; xr[n][2] = v.z; xr[n][3] = v.w;
      }
#pragma unroll
      for (int cc = 0; cc < 4; ++cc) {
        float kk[4];
#pragma unroll
        for (int k = 0; k < 4; ++k) kk[k] = K1[(size_t)(c0 + k) * CDIM + c + cc];
#pragma unroll
        for (int k = 0; k < 4; ++k)
#pragma unroll
          for (int n = 0; n < 6; ++n)
            acc[k][n] = fmaf(kk[k], xr[n][cc], acc[k][n]);
      }
    }
  }

  float xn[4][6], xo[4][6];
#pragma unroll
  for (int k = 0; k < 4; ++k)
#pragma unroll
    for (int n = 0; n < 6; ++n) {
      float v = fmaxf(acc[k][n], 0.0f);
      xn[k][n] = v; xo[k][n] = v;
    }

  const int PI[NPAIR] = {0,0,0,0,0,1,1,1,1,2,2,2,3,3,4};
  const int PJ[NPAIR] = {1,2,3,4,5,2,3,4,5,3,4,5,4,5,5};

  // ---- phase 2: 4 PDE iterations ----
#pragma unroll 1
  for (int it = 0; it < 4; ++it) {
    float sq[6], gp[NPAIR];
#pragma unroll
    for (int n = 0; n < 6; ++n) sq[n] = 0.0f;
#pragma unroll
    for (int p = 0; p < NPAIR; ++p) gp[p] = 0.0f;
#pragma unroll
    for (int k = 0; k < 4; ++k)
#pragma unroll
      for (int n = 0; n < 6; ++n) sq[n] = fmaf(xn[k][n], xn[k][n], sq[n]);
#pragma unroll
    for (int p = 0; p < NPAIR; ++p)
#pragma unroll
      for (int k = 0; k < 4; ++k) gp[p] = fmaf(xn[k][PI[p]], xn[k][PJ[p]], gp[p]);

    // 64-lane butterfly reduce (21 values)
#pragma unroll
    for (int s = 32; s >= 1; s >>= 1) {
#pragma unroll
      for (int n = 0; n < 6; ++n) sq[n] += __shfl_xor(sq[n], s, 64);
#pragma unroll
      for (int p = 0; p < NPAIR; ++p) gp[p] += __shfl_xor(gp[p], s, 64);
    }

    float D[NPAIR];
    float sumD = 0.0f;
#pragma unroll
    for (int p = 0; p < NPAIR; ++p) {
      D[p] = fmaxf(sq[PI[p]] + sq[PJ[p]] - 2.0f * gp[p], 0.0f);
      sumD += D[p];
    }
    float mean = sumD * (2.0f / 36.0f);
    float sc = 0.0f;
#pragma unroll
    for (int p = 0; p < NPAIR; ++p) {
      float dm = D[p] - mean;
      sc = fmaf(dm, dm, sc);
    }
    float var = (2.0f * sc + 6.0f * mean * mean) * (1.0f / 35.0f);
    float rstd = rsqrtf(var);

    float w[NPAIR];
#pragma unroll
    for (int p = 0; p < NPAIR; ++p) w[p] = __expf(-2.0f * D[p] * rstd);

    float dxn[4][6];
#pragma unroll
    for (int k = 0; k < 4; ++k)
#pragma unroll
      for (int n = 0; n < 6; ++n) dxn[k][n] = 0.0f;

#pragma unroll
    for (int p = 0; p < NPAIR; ++p) {
      const int i = PI[p], j = PJ[p];
#pragma unroll
      for (int k = 0; k < 4; ++k) {
        float d = tanh5(w[p] * (xn[k][j] - xn[k][i]));
        float wd = w[p] * d;
        dxn[k][j] += wd;
        dxn[k][i] -= wd;
      }
    }

#pragma unroll
    for (int k = 0; k < 4; ++k)
#pragma unroll
      for (int n = 0; n < 6; ++n) {
        float nv = cA * xn[k][n] + cB * xo[k][n] - invd * dxn[k][n];
        xo[k][n] = xn[k][n];
        xn[k][n] = nv;
      }
  }

  // ---- phase 3: out_b[n][o] = sum_c KNc[o,c]*xn[c,n] ----
  float po[6][6];
#pragma unroll
  for (int n = 0; n < 6; ++n)
#pragma unroll
    for (int o = 0; o < 6; ++o) po[n][o] = 0.0f;
#pragma unroll
  for (int k = 0; k < 4; ++k)
#pragma unroll
    for (int o = 0; o < 6; ++o) {
      float kv = KNc[(size_t)o * CDIM + c0 + k];
#pragma unroll
      for (int n = 0; n < 6; ++n) po[n][o] = fmaf(kv, xn[k][n], po[n][o]);
    }
#pragma unroll
  for (int s = 32; s >= 1; s >>= 1)
#pragma unroll
    for (int n = 0; n < 6; ++n)
#pragma unroll
      for (int o = 0; o < 6; ++o) po[n][o] += __shfl_xor(po[n][o], s, 64);

  if (lane == 0) {
#pragma unroll
    for (int n = 0; n < 6; ++n)
#pragma unroll
      for (int o = 0; o < 6; ++o) Ms[wv][n * 6 + o] = po[n][o];
  }
  __syncthreads();

  // out0: out[b,0,:]
  if (lane < 6) out[(size_t)b * 6 + lane] = Ms[wv][lane];

  // xn store: [b, c, n] contiguous; lane covers c in [c0, c0+4)
  {
    float4* d4 = reinterpret_cast<float4*>(out + XN_OFF + (size_t)b * (CDIM * NNODES) + (size_t)c0 * NNODES);
    d4[0] = make_float4(xn[0][0], xn[0][1], xn[0][2], xn[0][3]);
    d4[1] = make_float4(xn[0][4], xn[0][5], xn[1][0], xn[1][1]);
    d4[2] = make_float4(xn[1][2], xn[1][3], xn[1][4], xn[1][5]);
    d4[3] = make_float4(xn[2][0], xn[2][1], xn[2][2], xn[2][3]);
    d4[4] = make_float4(xn[2][4], xn[2][5], xn[3][0], xn[3][1]);
    d4[5] = make_float4(xn[3][2], xn[3][3], xn[3][4], xn[3][5]);
  }

  // Wl: nodes = 6 output channels, features over 6 graph nodes
  {
    const int p = lane;
    float Dp = 0.0f;
    int o1 = 0, o2 = 0;
    if (p < 36) {
      o1 = p / 6; o2 = p % 6;
#pragma unroll
      for (int n = 0; n < 6; ++n) {
        float diff = Ms[wv][n * 6 + o1] - Ms[wv][n * 6 + o2];
        Dp = fmaf(diff, diff, Dp);
      }
    }
    float sD = Dp;
#pragma unroll
    for (int s = 32; s >= 1; s >>= 1) sD += __shfl_xor(sD, s, 64);
    float meanl = sD * (1.0f / 36.0f);
    float c2 = 0.0f;
    if (p < 36) { float dm = Dp - meanl; c2 = dm * dm; }
    float sc2 = c2;
#pragma unroll
    for (int s = 32; s >= 1; s >>= 1) sc2 += __shfl_xor(sc2, s, 64);
    float rstdl = rsqrtf(sc2 * (1.0f / 35.0f));
    if (p < 36) {
      float wnew = __expf(-2.0f * Dp * rstdl) - ((o1 == o2) ? 10.0f : 0.0f);
      size_t base = WL_OFF + ((size_t)b * 36 + p) * 2;
      out[base] = (o1 == o2) ? 1.0f : 0.0f;
      out[base + 1] = wnew;
    }
  }
}

extern "C" void kernel_launch(void* const* d_in, const int* in_sizes, int n_in,
                              void* d_out, int out_size, void* d_ws, size_t ws_size,
                              hipStream_t stream) {
  (void)in_sizes; (void)n_in; (void)out_size;
  const float* x     = (const float*)d_in[0];
  const float* K1    = (const float*)d_in[1];
  const float* KNc   = (const float*)d_in[2];
  const float* alpha = (const float*)d_in[3];
  const float* h     = (const float*)d_in[4];
  float* out = (float*)d_out;
  float* K1T = (float*)d_ws;

  const bool useT = (ws_size >= 256 * 256 * sizeof(float));
  if (useT) {
    transpose_k1<<<256, 256, 0, stream>>>(K1, K1T);
    pdegcn_main<true><<<BTOT / 4, 256, 0, stream>>>(x, K1, K1T, KNc, alpha, h, out);
  } else {
    pdegcn_main<false><<<BTOT / 4, 256, 0, stream>>>(x, K1, K1T, KNc, alpha, h, out);
  }
}

// Round 2
// 214.995 us; speedup vs baseline: 2.0902x; 2.0902x over previous
//
#include <hip/hip_runtime.h>
#include <math.h>

#define NNODES 6
#define CDIM 256
#define NPAIR 15
#define BTOT 8192

// offsets in d_out (floats)
#define XN_OFF   49152ULL          // 8192*6
#define WL_OFF   12632064ULL       // 49152 + 8192*256*6

__global__ void transpose_k1(const float* __restrict__ K1, float* __restrict__ K1T) {
  int t = blockIdx.x * 256 + threadIdx.x;
  int o = t >> 8, c = t & 255;
  K1T[c * 256 + o] = K1[t];
}

template <bool USET>
__global__ __launch_bounds__(256) void pdegcn_main(
    const float* __restrict__ x,
    const float* __restrict__ K1,
    const float* __restrict__ K1T,
    const float* __restrict__ KNc,
    const float* __restrict__ alphap,
    const float* __restrict__ hp,
    float* __restrict__ out)
{
  __shared__ float kt[16 * CDIM];   // shared K1T tile (16 KiB)
  __shared__ float Tt[1025];        // tanh5 lookup table, x in [0, 8.0078], step 1/128
  __shared__ float Ms[4][36];       // per-wave final 6x6 out tile

  const int wv = threadIdx.x >> 6;
  const int lane = threadIdx.x & 63;
  const int b = blockIdx.x * 4 + wv;
  const int c0 = lane * 4;

  // ---- build tanh5 table (once per block) ----
  for (int i = threadIdx.x; i < 1025; i += 256) {
    float v = (float)i * (1.0f / 128.0f);
#pragma unroll
    for (int t = 0; t < 5; ++t) v = tanhf(v);
    Tt[i] = v;
  }
  __syncthreads();

  const float alpha = alphap[0];
  const float h = hp[0];
  const float beta = 1.0f / (1.0f + __expf(-alpha));
  const float al = (1.0f - beta) / h;
  const float be = beta / (h * h);
  const float invd = 1.0f / (be + al);
  const float cA = (2.0f * be + al) * invd;
  const float cB = -be * invd;

  const float* xb = x + (size_t)b * (NNODES * CDIM);

  // ---- phase 1: xn0[o,n] = relu(sum_c K1[o,c] * x[b,n,c]); lane owns o in [c0,c0+4) ----
  float acc[4][6];
#pragma unroll
  for (int k = 0; k < 4; ++k)
#pragma unroll
    for (int n = 0; n < 6; ++n) acc[k][n] = 0.0f;

  if (USET) {
#pragma unroll 1
    for (int ct = 0; ct < CDIM; ct += 16) {
      // stage K1T rows [ct, ct+16) into LDS, shared by the 4 waves
      const float4* src = reinterpret_cast<const float4*>(K1T + (size_t)ct * CDIM);
      float4* dstk = reinterpret_cast<float4*>(kt);
#pragma unroll
      for (int i = 0; i < 4; ++i) dstk[threadIdx.x + 256 * i] = src[threadIdx.x + 256 * i];
      __syncthreads();
#pragma unroll
      for (int c = 0; c < 16; c += 4) {
        float xr[6][4];
#pragma unroll
        for (int n = 0; n < 6; ++n) {
          // wave-uniform broadcast load, L1-resident after first touch
          float4 v = *reinterpret_cast<const float4*>(xb + n * CDIM + ct + c);
          xr[n][0] = v.x; xr[n][1] = v.y; xr[n][2] = v.z; xr[n][3] = v.w;
        }
#pragma unroll
        for (int cc = 0; cc < 4; ++cc) {
          float4 kv = *reinterpret_cast<const float4*>(&kt[(c + cc) * CDIM + c0]);
          float kk[4] = {kv.x, kv.y, kv.z, kv.w};
#pragma unroll
          for (int k = 0; k < 4; ++k)
#pragma unroll
            for (int n = 0; n < 6; ++n)
              acc[k][n] = fmaf(kk[k], xr[n][cc], acc[k][n]);
        }
      }
      __syncthreads();
    }
  } else {
    // fallback: direct (uncoalesced) K1 reads, correctness path if ws too small
#pragma unroll 1
    for (int c = 0; c < CDIM; c += 4) {
      float xr[6][4];
#pragma unroll
      for (int n = 0; n < 6; ++n) {
        float4 v = *reinterpret_cast<const float4*>(xb + n * CDIM + c);
        xr[n][0] = v.x; xr[n][1] = v.y; xr[n][2] = v.z; xr[n][3] = v.w;
      }
#pragma unroll
      for (int cc = 0; cc < 4; ++cc) {
        float kk[4];
#pragma unroll
        for (int k = 0; k < 4; ++k) kk[k] = K1[(size_t)(c0 + k) * CDIM + c + cc];
#pragma unroll
        for (int k = 0; k < 4; ++k)
#pragma unroll
          for (int n = 0; n < 6; ++n)
            acc[k][n] = fmaf(kk[k], xr[n][cc], acc[k][n]);
      }
    }
  }

  float xn[4][6], xo[4][6];
#pragma unroll
  for (int k = 0; k < 4; ++k)
#pragma unroll
    for (int n = 0; n < 6; ++n) {
      float v = fmaxf(acc[k][n], 0.0f);
      xn[k][n] = v; xo[k][n] = v;
    }

  const int PI[NPAIR] = {0,0,0,0,0,1,1,1,1,2,2,2,3,3,4};
  const int PJ[NPAIR] = {1,2,3,4,5,2,3,4,5,3,4,5,4,5,5};

  // ---- phase 2: 4 PDE iterations ----
#pragma unroll 1
  for (int it = 0; it < 4; ++it) {
    float sq[6], gp[NPAIR];
#pragma unroll
    for (int n = 0; n < 6; ++n) sq[n] = 0.0f;
#pragma unroll
    for (int p = 0; p < NPAIR; ++p) gp[p] = 0.0f;
#pragma unroll
    for (int k = 0; k < 4; ++k)
#pragma unroll
      for (int n = 0; n < 6; ++n) sq[n] = fmaf(xn[k][n], xn[k][n], sq[n]);
#pragma unroll
    for (int p = 0; p < NPAIR; ++p)
#pragma unroll
      for (int k = 0; k < 4; ++k) gp[p] = fmaf(xn[k][PI[p]], xn[k][PJ[p]], gp[p]);

    // 64-lane butterfly reduce (21 values)
#pragma unroll
    for (int s = 32; s >= 1; s >>= 1) {
#pragma unroll
      for (int n = 0; n < 6; ++n) sq[n] += __shfl_xor(sq[n], s, 64);
#pragma unroll
      for (int p = 0; p < NPAIR; ++p) gp[p] += __shfl_xor(gp[p], s, 64);
    }

    float D[NPAIR];
    float sumD = 0.0f;
#pragma unroll
    for (int p = 0; p < NPAIR; ++p) {
      D[p] = fmaxf(sq[PI[p]] + sq[PJ[p]] - 2.0f * gp[p], 0.0f);
      sumD += D[p];
    }
    float mean = sumD * (2.0f / 36.0f);
    float sc = 0.0f;
#pragma unroll
    for (int p = 0; p < NPAIR; ++p) {
      float dm = D[p] - mean;
      sc = fmaf(dm, dm, sc);
    }
    float var = (2.0f * sc + 6.0f * mean * mean) * (1.0f / 35.0f);
    float rstd = rsqrtf(var);

    float w[NPAIR];
#pragma unroll
    for (int p = 0; p < NPAIR; ++p) w[p] = __expf(-2.0f * D[p] * rstd);

    float dxn[4][6];
#pragma unroll
    for (int k = 0; k < 4; ++k)
#pragma unroll
      for (int n = 0; n < 6; ++n) dxn[k][n] = 0.0f;

#pragma unroll
    for (int p = 0; p < NPAIR; ++p) {
      const int i = PI[p], j = PJ[p];
      const float wp = w[p];
#pragma unroll
      for (int k = 0; k < 4; ++k) {
        float g = wp * (xn[k][j] - xn[k][i]);
        // tanh5 via LDS table + linear interp
        float ax = fminf(fabsf(g) * 128.0f, 1023.0f);
        int ii = (int)ax;
        float fr = ax - (float)ii;
        float ta = Tt[ii];
        float tb = Tt[ii + 1];
        float d = fmaf(fr, tb - ta, ta);
        d = copysignf(d, g);
        float wd = wp * d;
        dxn[k][j] += wd;
        dxn[k][i] -= wd;
      }
    }

#pragma unroll
    for (int k = 0; k < 4; ++k)
#pragma unroll
      for (int n = 0; n < 6; ++n) {
        float nv = cA * xn[k][n] + cB * xo[k][n] - invd * dxn[k][n];
        xo[k][n] = xn[k][n];
        xn[k][n] = nv;
      }
  }

  // ---- phase 3: out_b[n][o] = sum_c KNc[o,c]*xn[c,n] ----
  float po[6][6];
#pragma unroll
  for (int n = 0; n < 6; ++n)
#pragma unroll
    for (int o = 0; o < 6; ++o) po[n][o] = 0.0f;
#pragma unroll
  for (int k = 0; k < 4; ++k)
#pragma unroll
    for (int o = 0; o < 6; ++o) {
      float kv = KNc[(size_t)o * CDIM + c0 + k];
#pragma unroll
      for (int n = 0; n < 6; ++n) po[n][o] = fmaf(kv, xn[k][n], po[n][o]);
    }
#pragma unroll
  for (int s = 32; s >= 1; s >>= 1)
#pragma unroll
    for (int n = 0; n < 6; ++n)
#pragma unroll
      for (int o = 0; o < 6; ++o) po[n][o] += __shfl_xor(po[n][o], s, 64);

  if (lane == 0) {
#pragma unroll
    for (int n = 0; n < 6; ++n)
#pragma unroll
      for (int o = 0; o < 6; ++o) Ms[wv][n * 6 + o] = po[n][o];
  }
  __syncthreads();

  // out0: out[b,0,:]
  if (lane < 6) out[(size_t)b * 6 + lane] = Ms[wv][lane];

  // xn store: [b, c, n] contiguous; lane covers c in [c0, c0+4)
  {
    float4* d4 = reinterpret_cast<float4*>(out + XN_OFF + (size_t)b * (CDIM * NNODES) + (size_t)c0 * NNODES);
    d4[0] = make_float4(xn[0][0], xn[0][1], xn[0][2], xn[0][3]);
    d4[1] = make_float4(xn[0][4], xn[0][5], xn[1][0], xn[1][1]);
    d4[2] = make_float4(xn[1][2], xn[1][3], xn[1][4], xn[1][5]);
    d4[3] = make_float4(xn[2][0], xn[2][1], xn[2][2], xn[2][3]);
    d4[4] = make_float4(xn[2][4], xn[2][5], xn[3][0], xn[3][1]);
    d4[5] = make_float4(xn[3][2], xn[3][3], xn[3][4], xn[3][5]);
  }

  // Wl: nodes = 6 output channels, features over 6 graph nodes
  {
    const int p = lane;
    float Dp = 0.0f;
    int o1 = 0, o2 = 0;
    if (p < 36) {
      o1 = p / 6; o2 = p % 6;
#pragma unroll
      for (int n = 0; n < 6; ++n) {
        float diff = Ms[wv][n * 6 + o1] - Ms[wv][n * 6 + o2];
        Dp = fmaf(diff, diff, Dp);
      }
    }
    float sD = Dp;
#pragma unroll
    for (int s = 32; s >= 1; s >>= 1) sD += __shfl_xor(sD, s, 64);
    float meanl = sD * (1.0f / 36.0f);
    float c2 = 0.0f;
    if (p < 36) { float dm = Dp - meanl; c2 = dm * dm; }
    float sc2 = c2;
#pragma unroll
    for (int s = 32; s >= 1; s >>= 1) sc2 += __shfl_xor(sc2, s, 64);
    float rstdl = rsqrtf(sc2 * (1.0f / 35.0f));
    if (p < 36) {
      float wnew = __expf(-2.0f * Dp * rstdl) - ((o1 == o2) ? 10.0f : 0.0f);
      size_t base = WL_OFF + ((size_t)b * 36 + p) * 2;
      out[base] = (o1 == o2) ? 1.0f : 0.0f;
      out[base + 1] = wnew;
    }
  }
}

extern "C" void kernel_launch(void* const* d_in, const int* in_sizes, int n_in,
                              void* d_out, int out_size, void* d_ws, size_t ws_size,
                              hipStream_t stream) {
  (void)in_sizes; (void)n_in; (void)out_size;
  const float* x     = (const float*)d_in[0];
  const float* K1    = (const float*)d_in[1];
  const float* KNc   = (const float*)d_in[2];
  const float* alpha = (const float*)d_in[3];
  const float* h     = (const float*)d_in[4];
  float* out = (float*)d_out;
  float* K1T = (float*)d_ws;

  const bool useT = (ws_size >= 256 * 256 * sizeof(float));
  if (useT) {
    transpose_k1<<<256, 256, 0, stream>>>(K1, K1T);
    pdegcn_main<true><<<BTOT / 4, 256, 0, stream>>>(x, K1, K1T, KNc, alpha, h, out);
  } else {
    pdegcn_main<false><<<BTOT / 4, 256, 0, stream>>>(x, K1, K1T, KNc, alpha, h, out);
  }
}

// Round 3
// 150.418 us; speedup vs baseline: 2.9876x; 1.4293x over previous
//
#include <hip/hip_runtime.h>
#include <math.h>

#define NNODES 6
#define CDIM 256
#define NPAIR 15
#define BTOT 8192

// offsets in d_out (floats)
#define XN_OFF   49152ULL          // 8192*6
#define WL_OFF   12632064ULL       // 49152 + 8192*256*6

typedef __attribute__((ext_vector_type(8))) short short8v;   // 8 bf16 = 4 VGPR
typedef __attribute__((ext_vector_type(4))) float f32x4;

static __device__ __forceinline__ unsigned bf16_rne(float f) {
  unsigned u = __float_as_uint(f);
  return (u + 0x7FFFu + ((u >> 16) & 1u)) >> 16;
}

// ---- prep: split K1 (fp32) into bf16 hi/lo, laid out in MFMA A-fragment order ----
// A-frag addressing (16B units): idx16 = ((s*16 + mt)*4 + ko)*16 + row
//   s = c>>5, ko = (c>>3)&3, j = c&7, mt = o>>4, row = o&15
// so that lane l of wave reads Ah[(s*16+mt)*64 + l] -> A[row=l&15][k = s*32 + (l>>4)*8 + j]
__global__ void split_k1(const float* __restrict__ K1,
                         uint4* __restrict__ Ah, uint4* __restrict__ Al) {
  int t = blockIdx.x * 256 + threadIdx.x;    // 8192 threads
  int o = t >> 5, c8 = t & 31;
  const float* src = K1 + (size_t)o * 256 + c8 * 8;
  unsigned hi[8], lo[8];
#pragma unroll
  for (int j = 0; j < 8; ++j) {
    float f = src[j];
    unsigned hr = bf16_rne(f);
    float hf = __uint_as_float(hr << 16);
    lo[j] = bf16_rne(f - hf);
    hi[j] = hr;
  }
  int s = c8 >> 2, ko = c8 & 3, mt = o >> 4, row = o & 15;
  int idx16 = ((s * 16 + mt) * 4 + ko) * 16 + row;
  Ah[idx16] = make_uint4(hi[0] | (hi[1] << 16), hi[2] | (hi[3] << 16),
                         hi[4] | (hi[5] << 16), hi[6] | (hi[7] << 16));
  Al[idx16] = make_uint4(lo[0] | (lo[1] << 16), lo[2] | (lo[3] << 16),
                         lo[4] | (lo[5] << 16), lo[6] | (lo[7] << 16));
}

// ---- main kernel: 4 batches per block, 1 batch per wave for phases 2/3 ----
__global__ __launch_bounds__(256, 4) void pdegcn_mfma(
    const float* __restrict__ x,
    const uint4* __restrict__ Ahg,
    const uint4* __restrict__ Alg,
    const float* __restrict__ KNc,
    const float* __restrict__ alphap,
    const float* __restrict__ hp,
    float* __restrict__ out)
{
  // bbuf: x as bf16 hi/lo B-fragments: [split][ko 0..31][col 0..31 (XOR-swz)][j 0..7]
  // 16384 halfwords = 32 KB; later aliased as xn_lds[24][260] fp32 (24.96 KB)
  __shared__ unsigned short bbuf[16384];
  __shared__ float Tt[1025];     // tanh5 table, x in [0, 8.0078], step 1/128
  __shared__ float Ms[4][36];

  const int wv = threadIdx.x >> 6;
  const int lane = threadIdx.x & 63;
  const int b0 = blockIdx.x * 4;
  const int b = b0 + wv;

  // ---- build tanh5 table ----
  for (int i = threadIdx.x; i < 1025; i += 256) {
    float v = (float)i * (1.0f / 128.0f);
#pragma unroll
    for (int t = 0; t < 5; ++t) {
      float e = __expf(2.0f * v);
      v = 1.0f - __fdividef(2.0f, e + 1.0f);
    }
    Tt[i] = v;
  }

  // ---- stage x -> bf16 hi/lo B-fragments in LDS (XOR-swizzled col) ----
  {
    const float4* x4 = reinterpret_cast<const float4*>(x) + (size_t)b0 * 384;
#pragma unroll
    for (int i = 0; i < 6; ++i) {
      int idx = threadIdx.x + 256 * i;          // 1536 float4s: p = idx>>6, c4 = idx&63
      int p = idx >> 6, c4 = idx & 63;
      float4 v = x4[idx];
      float f[4] = {v.x, v.y, v.z, v.w};
      unsigned hh[4], ll[4];
#pragma unroll
      for (int j = 0; j < 4; ++j) {
        unsigned hr = bf16_rne(f[j]);
        float hf = __uint_as_float(hr << 16);
        ll[j] = bf16_rne(f[j] - hf);
        hh[j] = hr;
      }
      int ko = c4 >> 1, jb = (c4 & 1) * 4;
      int colS = p ^ (ko & 7);
      int hw = (ko * 32 + colS) * 8 + jb;
      *reinterpret_cast<uint2*>(&bbuf[hw]) =
          make_uint2(hh[0] | (hh[1] << 16), hh[2] | (hh[3] << 16));
      *reinterpret_cast<uint2*>(&bbuf[8192 + hw]) =
          make_uint2(ll[0] | (ll[1] << 16), ll[2] | (ll[3] << 16));
    }
  }
  __syncthreads();

  // ---- phase 1: MFMA  C[o, bn] = sum_c K1[o,c] * x[bn, c]  (M=256, N=24, K=256) ----
  // wave wv owns Mtiles wv*4 .. wv*4+3 (channels 64*wv .. 64*wv+63), both Ntiles.
  f32x4 acc[4][2];
#pragma unroll
  for (int m = 0; m < 4; ++m)
#pragma unroll
    for (int nt = 0; nt < 2; ++nt)
      acc[m][nt] = (f32x4){0.0f, 0.0f, 0.0f, 0.0f};

  const int g = lane >> 4, colx = lane & 15;
  const short8v* Ah8 = reinterpret_cast<const short8v*>(Ahg);
  const short8v* Al8 = reinterpret_cast<const short8v*>(Alg);
  const char* bb = reinterpret_cast<const char*>(bbuf);

#pragma unroll 2
  for (int s = 0; s < 8; ++s) {
    int ko = s * 4 + g;
    int q = ko & 7;
    short8v bh[2], bl[2];
#pragma unroll
    for (int nt = 0; nt < 2; ++nt) {
      int off16 = ko * 32 + ((nt * 16 + colx) ^ q);
      bh[nt] = *reinterpret_cast<const short8v*>(bb + off16 * 16);
      bl[nt] = *reinterpret_cast<const short8v*>(bb + 16384 + off16 * 16);
    }
#pragma unroll
    for (int m = 0; m < 4; ++m) {
      int mt = wv * 4 + m;
      int ai = (s * 16 + mt) * 64 + lane;
      short8v a_h = Ah8[ai];
      short8v a_l = Al8[ai];
#pragma unroll
      for (int nt = 0; nt < 2; ++nt) {
        acc[m][nt] = __builtin_amdgcn_mfma_f32_16x16x32_bf16(a_h, bh[nt], acc[m][nt], 0, 0, 0);
        acc[m][nt] = __builtin_amdgcn_mfma_f32_16x16x32_bf16(a_h, bl[nt], acc[m][nt], 0, 0, 0);
        acc[m][nt] = __builtin_amdgcn_mfma_f32_16x16x32_bf16(a_l, bh[nt], acc[m][nt], 0, 0, 0);
      }
    }
  }
  __syncthreads();   // all waves done reading bbuf; reuse as xn_lds

  // ---- redistribute xn0 (with relu) via LDS: xn_lds[bn][ch], pitch 260 ----
  float* xn_lds = reinterpret_cast<float*>(bbuf);
#pragma unroll
  for (int m = 0; m < 4; ++m) {
    int mt = wv * 4 + m;
#pragma unroll
    for (int nt = 0; nt < 2; ++nt) {
      int bn = nt * 16 + colx;
      if (bn < 24) {
        f32x4 v = acc[m][nt];
        float4 w4 = make_float4(fmaxf(v[0], 0.0f), fmaxf(v[1], 0.0f),
                                fmaxf(v[2], 0.0f), fmaxf(v[3], 0.0f));
        // C row = g*4 + r  ->  channel = mt*16 + g*4 + r (4 consecutive)
        *reinterpret_cast<float4*>(&xn_lds[bn * 260 + mt * 16 + g * 4]) = w4;
      }
    }
  }
  __syncthreads();

  // ---- phase 2 register layout: lane owns channels c0..c0+3 of its wave's batch ----
  const int c0 = lane * 4;
  float xn[4][6], xo[4][6];
#pragma unroll
  for (int n = 0; n < 6; ++n) {
    float4 t = *reinterpret_cast<const float4*>(&xn_lds[(wv * 6 + n) * 260 + c0]);
    xn[0][n] = t.x; xn[1][n] = t.y; xn[2][n] = t.z; xn[3][n] = t.w;
    xo[0][n] = t.x; xo[1][n] = t.y; xo[2][n] = t.z; xo[3][n] = t.w;
  }

  const float alpha = alphap[0];
  const float h = hp[0];
  const float beta = 1.0f / (1.0f + __expf(-alpha));
  const float al = (1.0f - beta) / h;
  const float be = beta / (h * h);
  const float invd = 1.0f / (be + al);
  const float cA = (2.0f * be + al) * invd;
  const float cB = -be * invd;

  const int PI[NPAIR] = {0,0,0,0,0,1,1,1,1,2,2,2,3,3,4};
  const int PJ[NPAIR] = {1,2,3,4,5,2,3,4,5,3,4,5,4,5,5};

#pragma unroll 1
  for (int it = 0; it < 4; ++it) {
    // direct pairwise sq-dist: D[p] = sum_c (xn[c,i]-xn[c,j])^2  (exactly >= 0)
    float D[NPAIR];
#pragma unroll
    for (int p = 0; p < NPAIR; ++p) D[p] = 0.0f;
#pragma unroll
    for (int p = 0; p < NPAIR; ++p) {
      const int i = PI[p], j = PJ[p];
#pragma unroll
      for (int k = 0; k < 4; ++k) {
        float df = xn[k][i] - xn[k][j];
        D[p] = fmaf(df, df, D[p]);
      }
    }
#pragma unroll
    for (int s = 32; s >= 1; s >>= 1)
#pragma unroll
      for (int p = 0; p < NPAIR; ++p) D[p] += __shfl_xor(D[p], s, 64);

    float sumD = 0.0f;
#pragma unroll
    for (int p = 0; p < NPAIR; ++p) sumD += D[p];
    float mean = sumD * (2.0f / 36.0f);
    float sc = 0.0f;
#pragma unroll
    for (int p = 0; p < NPAIR; ++p) {
      float dm = D[p] - mean;
      sc = fmaf(dm, dm, sc);
    }
    float var = (2.0f * sc + 6.0f * mean * mean) * (1.0f / 35.0f);
    float rstd = rsqrtf(var);

    float w[NPAIR];
#pragma unroll
    for (int p = 0; p < NPAIR; ++p) w[p] = __expf(-2.0f * D[p] * rstd);

    float dxn[4][6];
#pragma unroll
    for (int k = 0; k < 4; ++k)
#pragma unroll
      for (int n = 0; n < 6; ++n) dxn[k][n] = 0.0f;

#pragma unroll
    for (int p = 0; p < NPAIR; ++p) {
      const int i = PI[p], j = PJ[p];
      const float wp = w[p];
#pragma unroll
      for (int k = 0; k < 4; ++k) {
        float gg = wp * (xn[k][j] - xn[k][i]);
        float ax = fminf(fabsf(gg) * 128.0f, 1023.0f);
        int ii = (int)ax;
        float fr = ax - (float)ii;
        float ta = Tt[ii];
        float tb = Tt[ii + 1];
        float d = fmaf(fr, tb - ta, ta);
        d = copysignf(d, gg);
        float wd = wp * d;
        dxn[k][j] += wd;
        dxn[k][i] -= wd;
      }
    }

#pragma unroll
    for (int k = 0; k < 4; ++k)
#pragma unroll
      for (int n = 0; n < 6; ++n) {
        float nv = cA * xn[k][n] + cB * xo[k][n] - invd * dxn[k][n];
        xo[k][n] = xn[k][n];
        xn[k][n] = nv;
      }
  }

  // ---- phase 3: out_b[n][o] = sum_c KNc[o,c]*xn[c,n] ----
  float po[6][6];
#pragma unroll
  for (int n = 0; n < 6; ++n)
#pragma unroll
    for (int o = 0; o < 6; ++o) po[n][o] = 0.0f;
#pragma unroll
  for (int k = 0; k < 4; ++k)
#pragma unroll
    for (int o = 0; o < 6; ++o) {
      float kv = KNc[(size_t)o * CDIM + c0 + k];
#pragma unroll
      for (int n = 0; n < 6; ++n) po[n][o] = fmaf(kv, xn[k][n], po[n][o]);
    }
#pragma unroll
  for (int s = 32; s >= 1; s >>= 1)
#pragma unroll
    for (int n = 0; n < 6; ++n)
#pragma unroll
      for (int o = 0; o < 6; ++o) po[n][o] += __shfl_xor(po[n][o], s, 64);

  if (lane == 0) {
#pragma unroll
    for (int n = 0; n < 6; ++n)
#pragma unroll
      for (int o = 0; o < 6; ++o) Ms[wv][n * 6 + o] = po[n][o];
  }
  __syncthreads();

  // out0: out[b,0,:]
  if (lane < 6) out[(size_t)b * 6 + lane] = Ms[wv][lane];

  // xn store: [b, c, n] contiguous; lane covers c in [c0, c0+4)
  {
    float4* d4 = reinterpret_cast<float4*>(out + XN_OFF + (size_t)b * (CDIM * NNODES) + (size_t)c0 * NNODES);
    d4[0] = make_float4(xn[0][0], xn[0][1], xn[0][2], xn[0][3]);
    d4[1] = make_float4(xn[0][4], xn[0][5], xn[1][0], xn[1][1]);
    d4[2] = make_float4(xn[1][2], xn[1][3], xn[1][4], xn[1][5]);
    d4[3] = make_float4(xn[2][0], xn[2][1], xn[2][2], xn[2][3]);
    d4[4] = make_float4(xn[2][4], xn[2][5], xn[3][0], xn[3][1]);
    d4[5] = make_float4(xn[3][2], xn[3][3], xn[3][4], xn[3][5]);
  }

  // Wl
  {
    const int p = lane;
    float Dp = 0.0f;
    int o1 = 0, o2 = 0;
    if (p < 36) {
      o1 = p / 6; o2 = p % 6;
#pragma unroll
      for (int n = 0; n < 6; ++n) {
        float diff = Ms[wv][n * 6 + o1] - Ms[wv][n * 6 + o2];
        Dp = fmaf(diff, diff, Dp);
      }
    }
    float sD = Dp;
#pragma unroll
    for (int s = 32; s >= 1; s >>= 1) sD += __shfl_xor(sD, s, 64);
    float meanl = sD * (1.0f / 36.0f);
    float c2 = 0.0f;
    if (p < 36) { float dm = Dp - meanl; c2 = dm * dm; }
    float sc2 = c2;
#pragma unroll
    for (int s = 32; s >= 1; s >>= 1) sc2 += __shfl_xor(sc2, s, 64);
    float rstdl = rsqrtf(sc2 * (1.0f / 35.0f));
    if (p < 36) {
      float wnew = __expf(-2.0f * Dp * rstdl) - ((o1 == o2) ? 10.0f : 0.0f);
      size_t base = WL_OFF + ((size_t)b * 36 + p) * 2;
      out[base] = (o1 == o2) ? 1.0f : 0.0f;
      out[base + 1] = wnew;
    }
  }
}

// ---- fallback (ws too small): R2 VALU kernel with direct K1 reads ----
__global__ __launch_bounds__(256) void pdegcn_fallback(
    const float* __restrict__ x,
    const float* __restrict__ K1,
    const float* __restrict__ KNc,
    const float* __restrict__ alphap,
    const float* __restrict__ hp,
    float* __restrict__ out)
{
  __shared__ float Tt[1025];
  __shared__ float Ms[4][36];

  const int wv = threadIdx.x >> 6;
  const int lane = threadIdx.x & 63;
  const int b = blockIdx.x * 4 + wv;
  const int c0 = lane * 4;

  for (int i = threadIdx.x; i < 1025; i += 256) {
    float v = (float)i * (1.0f / 128.0f);
#pragma unroll
    for (int t = 0; t < 5; ++t) {
      float e = __expf(2.0f * v);
      v = 1.0f - __fdividef(2.0f, e + 1.0f);
    }
    Tt[i] = v;
  }
  __syncthreads();

  const float alpha = alphap[0];
  const float h = hp[0];
  const float beta = 1.0f / (1.0f + __expf(-alpha));
  const float al = (1.0f - beta) / h;
  const float be = beta / (h * h);
  const float invd = 1.0f / (be + al);
  const float cA = (2.0f * be + al) * invd;
  const float cB = -be * invd;

  const float* xb = x + (size_t)b * (NNODES * CDIM);

  float acc[4][6];
#pragma unroll
  for (int k = 0; k < 4; ++k)
#pragma unroll
    for (int n = 0; n < 6; ++n) acc[k][n] = 0.0f;

#pragma unroll 1
  for (int c = 0; c < CDIM; c += 4) {
    float xr[6][4];
#pragma unroll
    for (int n = 0; n < 6; ++n) {
      float4 v = *reinterpret_cast<const float4*>(xb + n * CDIM + c);
      xr[n][0] = v.x; xr[n][1] = v.y; xr[n][2] = v.z; xr[n][3] = v.w;
    }
#pragma unroll
    for (int cc = 0; cc < 4; ++cc) {
      float kk[4];
#pragma unroll
      for (int k = 0; k < 4; ++k) kk[k] = K1[(size_t)(c0 + k) * CDIM + c + cc];
#pragma unroll
      for (int k = 0; k < 4; ++k)
#pragma unroll
        for (int n = 0; n < 6; ++n)
          acc[k][n] = fmaf(kk[k], xr[n][cc], acc[k][n]);
    }
  }

  float xn[4][6], xo[4][6];
#pragma unroll
  for (int k = 0; k < 4; ++k)
#pragma unroll
    for (int n = 0; n < 6; ++n) {
      float v = fmaxf(acc[k][n], 0.0f);
      xn[k][n] = v; xo[k][n] = v;
    }

  const int PI[NPAIR] = {0,0,0,0,0,1,1,1,1,2,2,2,3,3,4};
  const int PJ[NPAIR] = {1,2,3,4,5,2,3,4,5,3,4,5,4,5,5};

#pragma unroll 1
  for (int it = 0; it < 4; ++it) {
    float D[NPAIR];
#pragma unroll
    for (int p = 0; p < NPAIR; ++p) D[p] = 0.0f;
#pragma unroll
    for (int p = 0; p < NPAIR; ++p) {
      const int i = PI[p], j = PJ[p];
#pragma unroll
      for (int k = 0; k < 4; ++k) {
        float df = xn[k][i] - xn[k][j];
        D[p] = fmaf(df, df, D[p]);
      }
    }
#pragma unroll
    for (int s = 32; s >= 1; s >>= 1)
#pragma unroll
      for (int p = 0; p < NPAIR; ++p) D[p] += __shfl_xor(D[p], s, 64);

    float sumD = 0.0f;
#pragma unroll
    for (int p = 0; p < NPAIR; ++p) sumD += D[p];
    float mean = sumD * (2.0f / 36.0f);
    float sc = 0.0f;
#pragma unroll
    for (int p = 0; p < NPAIR; ++p) {
      float dm = D[p] - mean;
      sc = fmaf(dm, dm, sc);
    }
    float var = (2.0f * sc + 6.0f * mean * mean) * (1.0f / 35.0f);
    float rstd = rsqrtf(var);

    float w[NPAIR];
#pragma unroll
    for (int p = 0; p < NPAIR; ++p) w[p] = __expf(-2.0f * D[p] * rstd);

    float dxn[4][6];
#pragma unroll
    for (int k = 0; k < 4; ++k)
#pragma unroll
      for (int n = 0; n < 6; ++n) dxn[k][n] = 0.0f;

#pragma unroll
    for (int p = 0; p < NPAIR; ++p) {
      const int i = PI[p], j = PJ[p];
      const float wp = w[p];
#pragma unroll
      for (int k = 0; k < 4; ++k) {
        float gg = wp * (xn[k][j] - xn[k][i]);
        float ax = fminf(fabsf(gg) * 128.0f, 1023.0f);
        int ii = (int)ax;
        float fr = ax - (float)ii;
        float ta = Tt[ii];
        float tb = Tt[ii + 1];
        float d = fmaf(fr, tb - ta, ta);
        d = copysignf(d, gg);
        float wd = wp * d;
        dxn[k][j] += wd;
        dxn[k][i] -= wd;
      }
    }

#pragma unroll
    for (int k = 0; k < 4; ++k)
#pragma unroll
      for (int n = 0; n < 6; ++n) {
        float nv = cA * xn[k][n] + cB * xo[k][n] - invd * dxn[k][n];
        xo[k][n] = xn[k][n];
        xn[k][n] = nv;
      }
  }

  float po[6][6];
#pragma unroll
  for (int n = 0; n < 6; ++n)
#pragma unroll
    for (int o = 0; o < 6; ++o) po[n][o] = 0.0f;
#pragma unroll
  for (int k = 0; k < 4; ++k)
#pragma unroll
    for (int o = 0; o < 6; ++o) {
      float kv = KNc[(size_t)o * CDIM + c0 + k];
#pragma unroll
      for (int n = 0; n < 6; ++n) po[n][o] = fmaf(kv, xn[k][n], po[n][o]);
    }
#pragma unroll
  for (int s = 32; s >= 1; s >>= 1)
#pragma unroll
    for (int n = 0; n < 6; ++n)
#pragma unroll
      for (int o = 0; o < 6; ++o) po[n][o] += __shfl_xor(po[n][o], s, 64);

  if (lane == 0) {
#pragma unroll
    for (int n = 0; n < 6; ++n)
#pragma unroll
      for (int o = 0; o < 6; ++o) Ms[wv][n * 6 + o] = po[n][o];
  }
  __syncthreads();

  if (lane < 6) out[(size_t)b * 6 + lane] = Ms[wv][lane];

  {
    float4* d4 = reinterpret_cast<float4*>(out + XN_OFF + (size_t)b * (CDIM * NNODES) + (size_t)c0 * NNODES);
    d4[0] = make_float4(xn[0][0], xn[0][1], xn[0][2], xn[0][3]);
    d4[1] = make_float4(xn[0][4], xn[0][5], xn[1][0], xn[1][1]);
    d4[2] = make_float4(xn[1][2], xn[1][3], xn[1][4], xn[1][5]);
    d4[3] = make_float4(xn[2][0], xn[2][1], xn[2][2], xn[2][3]);
    d4[4] = make_float4(xn[2][4], xn[2][5], xn[3][0], xn[3][1]);
    d4[5] = make_float4(xn[3][2], xn[3][3], xn[3][4], xn[3][5]);
  }

  {
    const int p = lane;
    float Dp = 0.0f;
    int o1 = 0, o2 = 0;
    if (p < 36) {
      o1 = p / 6; o2 = p % 6;
#pragma unroll
      for (int n = 0; n < 6; ++n) {
        float diff = Ms[wv][n * 6 + o1] - Ms[wv][n * 6 + o2];
        Dp = fmaf(diff, diff, Dp);
      }
    }
    float sD = Dp;
#pragma unroll
    for (int s = 32; s >= 1; s >>= 1) sD += __shfl_xor(sD, s, 64);
    float meanl = sD * (1.0f / 36.0f);
    float c2 = 0.0f;
    if (p < 36) { float dm = Dp - meanl; c2 = dm * dm; }
    float sc2 = c2;
#pragma unroll
    for (int s = 32; s >= 1; s >>= 1) sc2 += __shfl_xor(sc2, s, 64);
    float rstdl = rsqrtf(sc2 * (1.0f / 35.0f));
    if (p < 36) {
      float wnew = __expf(-2.0f * Dp * rstdl) - ((o1 == o2) ? 10.0f : 0.0f);
      size_t base = WL_OFF + ((size_t)b * 36 + p) * 2;
      out[base] = (o1 == o2) ? 1.0f : 0.0f;
      out[base + 1] = wnew;
    }
  }
}

extern "C" void kernel_launch(void* const* d_in, const int* in_sizes, int n_in,
                              void* d_out, int out_size, void* d_ws, size_t ws_size,
                              hipStream_t stream) {
  (void)in_sizes; (void)n_in; (void)out_size;
  const float* x     = (const float*)d_in[0];
  const float* K1    = (const float*)d_in[1];
  const float* KNc   = (const float*)d_in[2];
  const float* alpha = (const float*)d_in[3];
  const float* h     = (const float*)d_in[4];
  float* out = (float*)d_out;

  if (ws_size >= 262144) {
    uint4* Ah = (uint4*)d_ws;
    uint4* Al = Ah + 8192;
    split_k1<<<32, 256, 0, stream>>>(K1, Ah, Al);
    pdegcn_mfma<<<BTOT / 4, 256, 0, stream>>>(x, Ah, Al, KNc, alpha, h, out);
  } else {
    pdegcn_fallback<<<BTOT / 4, 256, 0, stream>>>(x, K1, KNc, alpha, h, out);
  }
}

// Round 4
// 140.164 us; speedup vs baseline: 3.2061x; 1.0732x over previous
//
#include <hip/hip_runtime.h>
#include <math.h>

#define NNODES 6
#define CDIM 256
#define NPAIR 15
#define BTOT 8192

// offsets in d_out (floats)
#define XN_OFF   49152ULL          // 8192*6
#define WL_OFF   12632064ULL       // 49152 + 8192*256*6

typedef __attribute__((ext_vector_type(8))) short short8v;   // 8 bf16 = 4 VGPR
typedef __attribute__((ext_vector_type(4))) float f32x4;

static __device__ __forceinline__ unsigned bf16_rne(float f) {
  unsigned u = __float_as_uint(f);
  return (u + 0x7FFFu + ((u >> 16) & 1u)) >> 16;
}

static __device__ __forceinline__ float tanh1(float v) {
  float e = __expf(2.0f * v);
  return 1.0f - __fdividef(2.0f, e + 1.0f);
}

// ---- prep: split K1 (fp32) into bf16 hi/lo, laid out in MFMA A-fragment order ----
__global__ void split_k1(const float* __restrict__ K1,
                         uint4* __restrict__ Ah, uint4* __restrict__ Al) {
  int t = blockIdx.x * 256 + threadIdx.x;    // 8192 threads
  int o = t >> 5, c8 = t & 31;
  const float* src = K1 + (size_t)o * 256 + c8 * 8;
  unsigned hi[8], lo[8];
#pragma unroll
  for (int j = 0; j < 8; ++j) {
    float f = src[j];
    unsigned hr = bf16_rne(f);
    float hf = __uint_as_float(hr << 16);
    lo[j] = bf16_rne(f - hf);
    hi[j] = hr;
  }
  int s = c8 >> 2, ko = c8 & 3, mt = o >> 4, row = o & 15;
  int idx16 = ((s * 16 + mt) * 4 + ko) * 16 + row;
  Ah[idx16] = make_uint4(hi[0] | (hi[1] << 16), hi[2] | (hi[3] << 16),
                         hi[4] | (hi[5] << 16), hi[6] | (hi[7] << 16));
  Al[idx16] = make_uint4(lo[0] | (lo[1] << 16), lo[2] | (lo[3] << 16),
                         lo[4] | (lo[5] << 16), lo[6] | (lo[7] << 16));
}

// ---- main kernel: 4 batches per block, 1 batch per wave for phases 2/3 ----
__global__ __launch_bounds__(256, 4) void pdegcn_mfma(
    const float* __restrict__ x,
    const uint4* __restrict__ Ahg,
    const uint4* __restrict__ Alg,
    const float* __restrict__ KNc,
    const float* __restrict__ alphap,
    const float* __restrict__ hp,
    float* __restrict__ out)
{
  // bbuf: phase1 = x as bf16 hi/lo B-fragments (32 KB);
  // then xn_lds[24][260] fp32; then output staging (24.6 KB + 1.2 KB + 96 B)
  __shared__ unsigned short bbuf[16384];
  __shared__ float2 Tt2[512];    // tanh5 table: (value, delta), x in [0,8), step 1/64
  __shared__ float Ms[4][36];

  const int wv = threadIdx.x >> 6;
  const int lane = threadIdx.x & 63;
  const int b0 = blockIdx.x * 4;
  const int b = b0 + wv;

  // ---- build tanh5 table ----
  for (int i = threadIdx.x; i < 512; i += 256) {
    float v0 = (float)i * (1.0f / 64.0f);
    float v1 = (float)(i + 1) * (1.0f / 64.0f);
#pragma unroll
    for (int t = 0; t < 5; ++t) { v0 = tanh1(v0); v1 = tanh1(v1); }
    Tt2[i] = make_float2(v0, v1 - v0);
  }

  // ---- stage x -> bf16 hi/lo B-fragments in LDS (XOR-swizzled col) ----
  {
    const float4* x4 = reinterpret_cast<const float4*>(x) + (size_t)b0 * 384;
#pragma unroll
    for (int i = 0; i < 6; ++i) {
      int idx = threadIdx.x + 256 * i;          // 1536 float4s: p = idx>>6, c4 = idx&63
      int p = idx >> 6, c4 = idx & 63;
      float4 v = x4[idx];
      float f[4] = {v.x, v.y, v.z, v.w};
      unsigned hh[4], ll[4];
#pragma unroll
      for (int j = 0; j < 4; ++j) {
        unsigned hr = bf16_rne(f[j]);
        float hf = __uint_as_float(hr << 16);
        ll[j] = bf16_rne(f[j] - hf);
        hh[j] = hr;
      }
      int ko = c4 >> 1, jb = (c4 & 1) * 4;
      int colS = p ^ (ko & 7);
      int hw = (ko * 32 + colS) * 8 + jb;
      *reinterpret_cast<uint2*>(&bbuf[hw]) =
          make_uint2(hh[0] | (hh[1] << 16), hh[2] | (hh[3] << 16));
      *reinterpret_cast<uint2*>(&bbuf[8192 + hw]) =
          make_uint2(ll[0] | (ll[1] << 16), ll[2] | (ll[3] << 16));
    }
  }
  __syncthreads();

  // ---- phase 1: MFMA  C[o, bn] = sum_c K1[o,c] * x[bn, c]  (M=256, N=24, K=256) ----
  f32x4 acc[4][2];
#pragma unroll
  for (int m = 0; m < 4; ++m)
#pragma unroll
    for (int nt = 0; nt < 2; ++nt)
      acc[m][nt] = (f32x4){0.0f, 0.0f, 0.0f, 0.0f};

  const int g = lane >> 4, colx = lane & 15;
  const short8v* Ah8 = reinterpret_cast<const short8v*>(Ahg);
  const short8v* Al8 = reinterpret_cast<const short8v*>(Alg);
  const char* bb = reinterpret_cast<const char*>(bbuf);

#pragma unroll 2
  for (int s = 0; s < 8; ++s) {
    int ko = s * 4 + g;
    int q = ko & 7;
    short8v bh[2], bl[2];
#pragma unroll
    for (int nt = 0; nt < 2; ++nt) {
      int off16 = ko * 32 + ((nt * 16 + colx) ^ q);
      bh[nt] = *reinterpret_cast<const short8v*>(bb + off16 * 16);
      bl[nt] = *reinterpret_cast<const short8v*>(bb + 16384 + off16 * 16);
    }
#pragma unroll
    for (int m = 0; m < 4; ++m) {
      int mt = wv * 4 + m;
      int ai = (s * 16 + mt) * 64 + lane;
      short8v a_h = Ah8[ai];
      short8v a_l = Al8[ai];
#pragma unroll
      for (int nt = 0; nt < 2; ++nt) {
        acc[m][nt] = __builtin_amdgcn_mfma_f32_16x16x32_bf16(a_h, bh[nt], acc[m][nt], 0, 0, 0);
        acc[m][nt] = __builtin_amdgcn_mfma_f32_16x16x32_bf16(a_h, bl[nt], acc[m][nt], 0, 0, 0);
        acc[m][nt] = __builtin_amdgcn_mfma_f32_16x16x32_bf16(a_l, bh[nt], acc[m][nt], 0, 0, 0);
      }
    }
  }
  __syncthreads();   // all waves done reading bbuf; reuse as xn_lds

  // ---- redistribute xn0 (with relu) via LDS: xn_lds[bn][ch], pitch 260 ----
  float* xn_lds = reinterpret_cast<float*>(bbuf);
#pragma unroll
  for (int m = 0; m < 4; ++m) {
    int mt = wv * 4 + m;
#pragma unroll
    for (int nt = 0; nt < 2; ++nt) {
      int bn = nt * 16 + colx;
      if (bn < 24) {
        f32x4 v = acc[m][nt];
        float4 w4 = make_float4(fmaxf(v[0], 0.0f), fmaxf(v[1], 0.0f),
                                fmaxf(v[2], 0.0f), fmaxf(v[3], 0.0f));
        *reinterpret_cast<float4*>(&xn_lds[bn * 260 + mt * 16 + g * 4]) = w4;
      }
    }
  }
  __syncthreads();

  // ---- phase 2 register layout: lane owns channels c0..c0+3 of its wave's batch ----
  const int c0 = lane * 4;
  float xn[4][6], xo[4][6];
#pragma unroll
  for (int n = 0; n < 6; ++n) {
    float4 t = *reinterpret_cast<const float4*>(&xn_lds[(wv * 6 + n) * 260 + c0]);
    xn[0][n] = t.x; xn[1][n] = t.y; xn[2][n] = t.z; xn[3][n] = t.w;
    xo[0][n] = t.x; xo[1][n] = t.y; xo[2][n] = t.z; xo[3][n] = t.w;
  }

  const float alpha = alphap[0];
  const float h = hp[0];
  const float beta = 1.0f / (1.0f + __expf(-alpha));
  const float al = (1.0f - beta) / h;
  const float be = beta / (h * h);
  const float invd = 1.0f / (be + al);
  const float cA = (2.0f * be + al) * invd;
  const float cB = -be * invd;

  const int PI[NPAIR] = {0,0,0,0,0,1,1,1,1,2,2,2,3,3,4};
  const int PJ[NPAIR] = {1,2,3,4,5,2,3,4,5,3,4,5,4,5,5};

#pragma unroll 1
  for (int it = 0; it < 4; ++it) {
    float D[NPAIR];
#pragma unroll
    for (int p = 0; p < NPAIR; ++p) D[p] = 0.0f;
#pragma unroll
    for (int p = 0; p < NPAIR; ++p) {
      const int i = PI[p], j = PJ[p];
#pragma unroll
      for (int k = 0; k < 4; ++k) {
        float df = xn[k][i] - xn[k][j];
        D[p] = fmaf(df, df, D[p]);
      }
    }
#pragma unroll
    for (int s = 32; s >= 1; s >>= 1)
#pragma unroll
      for (int p = 0; p < NPAIR; ++p) D[p] += __shfl_xor(D[p], s, 64);

    float sumD = 0.0f;
#pragma unroll
    for (int p = 0; p < NPAIR; ++p) sumD += D[p];
    float mean = sumD * (2.0f / 36.0f);
    float sc = 0.0f;
#pragma unroll
    for (int p = 0; p < NPAIR; ++p) {
      float dm = D[p] - mean;
      sc = fmaf(dm, dm, sc);
    }
    float var = (2.0f * sc + 6.0f * mean * mean) * (1.0f / 35.0f);
    float rstd = rsqrtf(var);

    float w[NPAIR];
#pragma unroll
    for (int p = 0; p < NPAIR; ++p) w[p] = __expf(-2.0f * D[p] * rstd);

    float dxn[4][6];
#pragma unroll
    for (int k = 0; k < 4; ++k)
#pragma unroll
      for (int n = 0; n < 6; ++n) dxn[k][n] = 0.0f;

#pragma unroll
    for (int p = 0; p < NPAIR; ++p) {
      const int i = PI[p], j = PJ[p];
      const float wp = w[p];
#pragma unroll
      for (int k = 0; k < 4; ++k) {
        float gg = wp * (xn[k][j] - xn[k][i]);
        float ax = fminf(fabsf(gg) * 64.0f, 511.0f);
        int ii = (int)ax;
        float fr = ax - (float)ii;
        float2 tt = Tt2[ii];
        float d = fmaf(fr, tt.y, tt.x);
        d = copysignf(d, gg);
        float wd = wp * d;
        dxn[k][j] += wd;
        dxn[k][i] -= wd;
      }
    }

#pragma unroll
    for (int k = 0; k < 4; ++k)
#pragma unroll
      for (int n = 0; n < 6; ++n) {
        float nv = cA * xn[k][n] + cB * xo[k][n] - invd * dxn[k][n];
        xo[k][n] = xn[k][n];
        xn[k][n] = nv;
      }
  }

  // ---- phase 3: out_b[n][o] = sum_c KNc[o,c]*xn[c,n] ----
  float po[6][6];
#pragma unroll
  for (int n = 0; n < 6; ++n)
#pragma unroll
    for (int o = 0; o < 6; ++o) po[n][o] = 0.0f;
#pragma unroll
  for (int k = 0; k < 4; ++k)
#pragma unroll
    for (int o = 0; o < 6; ++o) {
      float kv = KNc[(size_t)o * CDIM + c0 + k];
#pragma unroll
      for (int n = 0; n < 6; ++n) po[n][o] = fmaf(kv, xn[k][n], po[n][o]);
    }
#pragma unroll
  for (int s = 32; s >= 1; s >>= 1)
#pragma unroll
    for (int n = 0; n < 6; ++n)
#pragma unroll
      for (int o = 0; o < 6; ++o) po[n][o] += __shfl_xor(po[n][o], s, 64);

  if (lane == 0) {
#pragma unroll
    for (int n = 0; n < 6; ++n)
#pragma unroll
      for (int o = 0; o < 6; ++o) Ms[wv][n * 6 + o] = po[n][o];
  }
  __syncthreads();   // Ms ready; all waves done with xn_lds -> bbuf reusable as staging

  // ---- stage all outputs into LDS in exact output order ----
  float* stg   = reinterpret_cast<float*>(bbuf);        // [4][1536] xn, 24576 B
  float* wstg  = stg + 6144;                            // [4][72]   Wl,  1152 B
  float* o0stg = wstg + 288;                            // [4][6]    out0,  96 B

  {
    float4* sp = reinterpret_cast<float4*>(stg) + wv * 384 + lane * 6;
    sp[0] = make_float4(xn[0][0], xn[0][1], xn[0][2], xn[0][3]);
    sp[1] = make_float4(xn[0][4], xn[0][5], xn[1][0], xn[1][1]);
    sp[2] = make_float4(xn[1][2], xn[1][3], xn[1][4], xn[1][5]);
    sp[3] = make_float4(xn[2][0], xn[2][1], xn[2][2], xn[2][3]);
    sp[4] = make_float4(xn[2][4], xn[2][5], xn[3][0], xn[3][1]);
    sp[5] = make_float4(xn[3][2], xn[3][3], xn[3][4], xn[3][5]);
  }

  if (lane < 6) o0stg[wv * 6 + lane] = Ms[wv][lane];

  {
    const int p = lane;
    float Dp = 0.0f;
    int o1 = 0, o2 = 0;
    if (p < 36) {
      o1 = p / 6; o2 = p % 6;
#pragma unroll
      for (int n = 0; n < 6; ++n) {
        float diff = Ms[wv][n * 6 + o1] - Ms[wv][n * 6 + o2];
        Dp = fmaf(diff, diff, Dp);
      }
    }
    float sD = Dp;
#pragma unroll
    for (int s = 32; s >= 1; s >>= 1) sD += __shfl_xor(sD, s, 64);
    float meanl = sD * (1.0f / 36.0f);
    float c2 = 0.0f;
    if (p < 36) { float dm = Dp - meanl; c2 = dm * dm; }
    float sc2 = c2;
#pragma unroll
    for (int s = 32; s >= 1; s >>= 1) sc2 += __shfl_xor(sc2, s, 64);
    float rstdl = rsqrtf(sc2 * (1.0f / 35.0f));
    if (p < 36) {
      float wnew = __expf(-2.0f * Dp * rstdl) - ((o1 == o2) ? 10.0f : 0.0f);
      wstg[wv * 72 + p * 2]     = (o1 == o2) ? 1.0f : 0.0f;
      wstg[wv * 72 + p * 2 + 1] = wnew;
    }
  }
  __syncthreads();

  // ---- coalesced block-contiguous output copies ----
  {
    const float4* s4 = reinterpret_cast<const float4*>(stg);
    float4* dst4 = reinterpret_cast<float4*>(out + XN_OFF) + (size_t)b0 * 384;
#pragma unroll
    for (int i = 0; i < 6; ++i)
      dst4[threadIdx.x + 256 * i] = s4[threadIdx.x + 256 * i];
  }
  if (threadIdx.x < 72) {
    float4* wdst = reinterpret_cast<float4*>(out + WL_OFF + (size_t)b0 * 72);
    wdst[threadIdx.x] = reinterpret_cast<const float4*>(wstg)[threadIdx.x];
  }
  if (threadIdx.x < 6) {
    float4* odst = reinterpret_cast<float4*>(out + (size_t)b0 * 6);
    odst[threadIdx.x] = reinterpret_cast<const float4*>(o0stg)[threadIdx.x];
  }
}

// ---- fallback (ws too small): R2 VALU kernel with direct K1 reads ----
__global__ __launch_bounds__(256) void pdegcn_fallback(
    const float* __restrict__ x,
    const float* __restrict__ K1,
    const float* __restrict__ KNc,
    const float* __restrict__ alphap,
    const float* __restrict__ hp,
    float* __restrict__ out)
{
  __shared__ float Tt[1025];
  __shared__ float Ms[4][36];

  const int wv = threadIdx.x >> 6;
  const int lane = threadIdx.x & 63;
  const int b = blockIdx.x * 4 + wv;
  const int c0 = lane * 4;

  for (int i = threadIdx.x; i < 1025; i += 256) {
    float v = (float)i * (1.0f / 128.0f);
#pragma unroll
    for (int t = 0; t < 5; ++t) {
      float e = __expf(2.0f * v);
      v = 1.0f - __fdividef(2.0f, e + 1.0f);
    }
    Tt[i] = v;
  }
  __syncthreads();

  const float alpha = alphap[0];
  const float h = hp[0];
  const float beta = 1.0f / (1.0f + __expf(-alpha));
  const float al = (1.0f - beta) / h;
  const float be = beta / (h * h);
  const float invd = 1.0f / (be + al);
  const float cA = (2.0f * be + al) * invd;
  const float cB = -be * invd;

  const float* xb = x + (size_t)b * (NNODES * CDIM);

  float acc[4][6];
#pragma unroll
  for (int k = 0; k < 4; ++k)
#pragma unroll
    for (int n = 0; n < 6; ++n) acc[k][n] = 0.0f;

#pragma unroll 1
  for (int c = 0; c < CDIM; c += 4) {
    float xr[6][4];
#pragma unroll
    for (int n = 0; n < 6; ++n) {
      float4 v = *reinterpret_cast<const float4*>(xb + n * CDIM + c);
      xr[n][0] = v.x; xr[n][1] = v.y; xr[n][2] = v.z; xr[n][3] = v.w;
    }
#pragma unroll
    for (int cc = 0; cc < 4; ++cc) {
      float kk[4];
#pragma unroll
      for (int k = 0; k < 4; ++k) kk[k] = K1[(size_t)(c0 + k) * CDIM + c + cc];
#pragma unroll
      for (int k = 0; k < 4; ++k)
#pragma unroll
        for (int n = 0; n < 6; ++n)
          acc[k][n] = fmaf(kk[k], xr[n][cc], acc[k][n]);
    }
  }

  float xn[4][6], xo[4][6];
#pragma unroll
  for (int k = 0; k < 4; ++k)
#pragma unroll
    for (int n = 0; n < 6; ++n) {
      float v = fmaxf(acc[k][n], 0.0f);
      xn[k][n] = v; xo[k][n] = v;
    }

  const int PI[NPAIR] = {0,0,0,0,0,1,1,1,1,2,2,2,3,3,4};
  const int PJ[NPAIR] = {1,2,3,4,5,2,3,4,5,3,4,5,4,5,5};

#pragma unroll 1
  for (int it = 0; it < 4; ++it) {
    float D[NPAIR];
#pragma unroll
    for (int p = 0; p < NPAIR; ++p) D[p] = 0.0f;
#pragma unroll
    for (int p = 0; p < NPAIR; ++p) {
      const int i = PI[p], j = PJ[p];
#pragma unroll
      for (int k = 0; k < 4; ++k) {
        float df = xn[k][i] - xn[k][j];
        D[p] = fmaf(df, df, D[p]);
      }
    }
#pragma unroll
    for (int s = 32; s >= 1; s >>= 1)
#pragma unroll
      for (int p = 0; p < NPAIR; ++p) D[p] += __shfl_xor(D[p], s, 64);

    float sumD = 0.0f;
#pragma unroll
    for (int p = 0; p < NPAIR; ++p) sumD += D[p];
    float mean = sumD * (2.0f / 36.0f);
    float sc = 0.0f;
#pragma unroll
    for (int p = 0; p < NPAIR; ++p) {
      float dm = D[p] - mean;
      sc = fmaf(dm, dm, sc);
    }
    float var = (2.0f * sc + 6.0f * mean * mean) * (1.0f / 35.0f);
    float rstd = rsqrtf(var);

    float w[NPAIR];
#pragma unroll
    for (int p = 0; p < NPAIR; ++p) w[p] = __expf(-2.0f * D[p] * rstd);

    float dxn[4][6];
#pragma unroll
    for (int k = 0; k < 4; ++k)
#pragma unroll
      for (int n = 0; n < 6; ++n) dxn[k][n] = 0.0f;

#pragma unroll
    for (int p = 0; p < NPAIR; ++p) {
      const int i = PI[p], j = PJ[p];
      const float wp = w[p];
#pragma unroll
      for (int k = 0; k < 4; ++k) {
        float gg = wp * (xn[k][j] - xn[k][i]);
        float ax = fminf(fabsf(gg) * 128.0f, 1023.0f);
        int ii = (int)ax;
        float fr = ax - (float)ii;
        float ta = Tt[ii];
        float tb = Tt[ii + 1];
        float d = fmaf(fr, tb - ta, ta);
        d = copysignf(d, gg);
        float wd = wp * d;
        dxn[k][j] += wd;
        dxn[k][i] -= wd;
      }
    }

#pragma unroll
    for (int k = 0; k < 4; ++k)
#pragma unroll
      for (int n = 0; n < 6; ++n) {
        float nv = cA * xn[k][n] + cB * xo[k][n] - invd * dxn[k][n];
        xo[k][n] = xn[k][n];
        xn[k][n] = nv;
      }
  }

  float po[6][6];
#pragma unroll
  for (int n = 0; n < 6; ++n)
#pragma unroll
    for (int o = 0; o < 6; ++o) po[n][o] = 0.0f;
#pragma unroll
  for (int k = 0; k < 4; ++k)
#pragma unroll
    for (int o = 0; o < 6; ++o) {
      float kv = KNc[(size_t)o * CDIM + c0 + k];
#pragma unroll
      for (int n = 0; n < 6; ++n) po[n][o] = fmaf(kv, xn[k][n], po[n][o]);
    }
#pragma unroll
  for (int s = 32; s >= 1; s >>= 1)
#pragma unroll
    for (int n = 0; n < 6; ++n)
#pragma unroll
      for (int o = 0; o < 6; ++o) po[n][o] += __shfl_xor(po[n][o], s, 64);

  if (lane == 0) {
#pragma unroll
    for (int n = 0; n < 6; ++n)
#pragma unroll
      for (int o = 0; o < 6; ++o) Ms[wv][n * 6 + o] = po[n][o];
  }
  __syncthreads();

  if (lane < 6) out[(size_t)b * 6 + lane] = Ms[wv][lane];

  {
    float4* d4 = reinterpret_cast<float4*>(out + XN_OFF + (size_t)b * (CDIM * NNODES) + (size_t)c0 * NNODES);
    d4[0] = make_float4(xn[0][0], xn[0][1], xn[0][2], xn[0][3]);
    d4[1] = make_float4(xn[0][4], xn[0][5], xn[1][0], xn[1][1]);
    d4[2] = make_float4(xn[1][2], xn[1][3], xn[1][4], xn[1][5]);
    d4[3] = make_float4(xn[2][0], xn[2][1], xn[2][2], xn[2][3]);
    d4[4] = make_float4(xn[2][4], xn[2][5], xn[3][0], xn[3][1]);
    d4[5] = make_float4(xn[3][2], xn[3][3], xn[3][4], xn[3][5]);
  }

  {
    const int p = lane;
    float Dp = 0.0f;
    int o1 = 0, o2 = 0;
    if (p < 36) {
      o1 = p / 6; o2 = p % 6;
#pragma unroll
      for (int n = 0; n < 6; ++n) {
        float diff = Ms[wv][n * 6 + o1] - Ms[wv][n * 6 + o2];
        Dp = fmaf(diff, diff, Dp);
      }
    }
    float sD = Dp;
#pragma unroll
    for (int s = 32; s >= 1; s >>= 1) sD += __shfl_xor(sD, s, 64);
    float meanl = sD * (1.0f / 36.0f);
    float c2 = 0.0f;
    if (p < 36) { float dm = Dp - meanl; c2 = dm * dm; }
    float sc2 = c2;
#pragma unroll
    for (int s = 32; s >= 1; s >>= 1) sc2 += __shfl_xor(sc2, s, 64);
    float rstdl = rsqrtf(sc2 * (1.0f / 35.0f));
    if (p < 36) {
      float wnew = __expf(-2.0f * Dp * rstdl) - ((o1 == o2) ? 10.0f : 0.0f);
      size_t base = WL_OFF + ((size_t)b * 36 + p) * 2;
      out[base] = (o1 == o2) ? 1.0f : 0.0f;
      out[base + 1] = wnew;
    }
  }
}

extern "C" void kernel_launch(void* const* d_in, const int* in_sizes, int n_in,
                              void* d_out, int out_size, void* d_ws, size_t ws_size,
                              hipStream_t stream) {
  (void)in_sizes; (void)n_in; (void)out_size;
  const float* x     = (const float*)d_in[0];
  const float* K1    = (const float*)d_in[1];
  const float* KNc   = (const float*)d_in[2];
  const float* alpha = (const float*)d_in[3];
  const float* h     = (const float*)d_in[4];
  float* out = (float*)d_out;

  if (ws_size >= 262144) {
    uint4* Ah = (uint4*)d_ws;
    uint4* Al = Ah + 8192;
    split_k1<<<32, 256, 0, stream>>>(K1, Ah, Al);
    pdegcn_mfma<<<BTOT / 4, 256, 0, stream>>>(x, Ah, Al, KNc, alpha, h, out);
  } else {
    pdegcn_fallback<<<BTOT / 4, 256, 0, stream>>>(x, K1, KNc, alpha, h, out);
  }
}

// Round 5
// 128.075 us; speedup vs baseline: 3.5088x; 1.0944x over previous
//
#include <hip/hip_runtime.h>
#include <math.h>

#define NNODES 6
#define CDIM 256
#define NPAIR 15
#define BTOT 8192

// offsets in d_out (floats)
#define XN_OFF   49152ULL          // 8192*6
#define WL_OFF   12632064ULL       // 49152 + 8192*256*6

typedef __attribute__((ext_vector_type(8))) short short8v;   // 8 bf16 = 4 VGPR
typedef __attribute__((ext_vector_type(4))) float f32x4;

static __device__ __forceinline__ unsigned bf16_rne(float f) {
  unsigned u = __float_as_uint(f);
  return (u + 0x7FFFu + ((u >> 16) & 1u)) >> 16;
}

static __device__ __forceinline__ float tanh1(float v) {
  float e = __expf(2.0f * v);
  return 1.0f - __fdividef(2.0f, e + 1.0f);
}

// ---- prep: split K1 (fp32) into bf16 hi/lo, laid out in MFMA A-fragment order ----
__global__ void split_k1(const float* __restrict__ K1,
                         uint4* __restrict__ Ah, uint4* __restrict__ Al) {
  int t = blockIdx.x * 256 + threadIdx.x;    // 8192 threads
  int o = t >> 5, c8 = t & 31;
  const float* src = K1 + (size_t)o * 256 + c8 * 8;
  unsigned hi[8], lo[8];
#pragma unroll
  for (int j = 0; j < 8; ++j) {
    float f = src[j];
    unsigned hr = bf16_rne(f);
    float hf = __uint_as_float(hr << 16);
    lo[j] = bf16_rne(f - hf);
    hi[j] = hr;
  }
  int s = c8 >> 2, ko = c8 & 3, mt = o >> 4, row = o & 15;
  int idx16 = ((s * 16 + mt) * 4 + ko) * 16 + row;
  Ah[idx16] = make_uint4(hi[0] | (hi[1] << 16), hi[2] | (hi[3] << 16),
                         hi[4] | (hi[5] << 16), hi[6] | (hi[7] << 16));
  Al[idx16] = make_uint4(lo[0] | (lo[1] << 16), lo[2] | (lo[3] << 16),
                         lo[4] | (lo[5] << 16), lo[6] | (lo[7] << 16));
}

// ---- main kernel: 4 batches per block, 1 batch per wave for phases 2/3 ----
// launch_bounds(256, 2): 256 unified VGPR/wave budget -> NO scratch spill.
// (256,4) capped at 128 regs/wave and spilled ~50 regs inside the PDE loop,
// costing ~200 MB of scratch WRITE traffic (R4 counters).
__global__ __launch_bounds__(256, 2) void pdegcn_mfma(
    const float* __restrict__ x,
    const uint4* __restrict__ Ahg,
    const uint4* __restrict__ Alg,
    const float* __restrict__ KNc,
    const float* __restrict__ alphap,
    const float* __restrict__ hp,
    float* __restrict__ out)
{
  // bbuf: phase1 = x as bf16 hi/lo B-fragments (32 KB);
  // then xn_lds[24][260] fp32; then output staging (24.6 KB + 1.2 KB + 96 B)
  __shared__ unsigned short bbuf[16384];
  __shared__ float2 Tt2[512];    // tanh5 table: (value, delta), x in [0,8), step 1/64
  __shared__ float Ms[4][36];

  const int wv = threadIdx.x >> 6;
  const int lane = threadIdx.x & 63;
  const int b0 = blockIdx.x * 4;
  const int b = b0 + wv;

  // ---- build tanh5 table ----
  for (int i = threadIdx.x; i < 512; i += 256) {
    float v0 = (float)i * (1.0f / 64.0f);
    float v1 = (float)(i + 1) * (1.0f / 64.0f);
#pragma unroll
    for (int t = 0; t < 5; ++t) { v0 = tanh1(v0); v1 = tanh1(v1); }
    Tt2[i] = make_float2(v0, v1 - v0);
  }

  // ---- stage x -> bf16 hi/lo B-fragments in LDS (XOR-swizzled col) ----
  {
    const float4* x4 = reinterpret_cast<const float4*>(x) + (size_t)b0 * 384;
#pragma unroll
    for (int i = 0; i < 6; ++i) {
      int idx = threadIdx.x + 256 * i;          // 1536 float4s: p = idx>>6, c4 = idx&63
      int p = idx >> 6, c4 = idx & 63;
      float4 v = x4[idx];
      float f[4] = {v.x, v.y, v.z, v.w};
      unsigned hh[4], ll[4];
#pragma unroll
      for (int j = 0; j < 4; ++j) {
        unsigned hr = bf16_rne(f[j]);
        float hf = __uint_as_float(hr << 16);
        ll[j] = bf16_rne(f[j] - hf);
        hh[j] = hr;
      }
      int ko = c4 >> 1, jb = (c4 & 1) * 4;
      int colS = p ^ (ko & 7);
      int hw = (ko * 32 + colS) * 8 + jb;
      *reinterpret_cast<uint2*>(&bbuf[hw]) =
          make_uint2(hh[0] | (hh[1] << 16), hh[2] | (hh[3] << 16));
      *reinterpret_cast<uint2*>(&bbuf[8192 + hw]) =
          make_uint2(ll[0] | (ll[1] << 16), ll[2] | (ll[3] << 16));
    }
  }
  __syncthreads();

  // ---- phase 1: MFMA  C[o, bn] = sum_c K1[o,c] * x[bn, c]  (M=256, N=24, K=256) ----
  f32x4 acc[4][2];
#pragma unroll
  for (int m = 0; m < 4; ++m)
#pragma unroll
    for (int nt = 0; nt < 2; ++nt)
      acc[m][nt] = (f32x4){0.0f, 0.0f, 0.0f, 0.0f};

  const int g = lane >> 4, colx = lane & 15;
  const short8v* Ah8 = reinterpret_cast<const short8v*>(Ahg);
  const short8v* Al8 = reinterpret_cast<const short8v*>(Alg);
  const char* bb = reinterpret_cast<const char*>(bbuf);

#pragma unroll 2
  for (int s = 0; s < 8; ++s) {
    int ko = s * 4 + g;
    int q = ko & 7;
    short8v bh[2], bl[2];
#pragma unroll
    for (int nt = 0; nt < 2; ++nt) {
      int off16 = ko * 32 + ((nt * 16 + colx) ^ q);
      bh[nt] = *reinterpret_cast<const short8v*>(bb + off16 * 16);
      bl[nt] = *reinterpret_cast<const short8v*>(bb + 16384 + off16 * 16);
    }
#pragma unroll
    for (int m = 0; m < 4; ++m) {
      int mt = wv * 4 + m;
      int ai = (s * 16 + mt) * 64 + lane;
      short8v a_h = Ah8[ai];
      short8v a_l = Al8[ai];
#pragma unroll
      for (int nt = 0; nt < 2; ++nt) {
        acc[m][nt] = __builtin_amdgcn_mfma_f32_16x16x32_bf16(a_h, bh[nt], acc[m][nt], 0, 0, 0);
        acc[m][nt] = __builtin_amdgcn_mfma_f32_16x16x32_bf16(a_h, bl[nt], acc[m][nt], 0, 0, 0);
        acc[m][nt] = __builtin_amdgcn_mfma_f32_16x16x32_bf16(a_l, bh[nt], acc[m][nt], 0, 0, 0);
      }
    }
  }
  __syncthreads();   // all waves done reading bbuf; reuse as xn_lds

  // ---- redistribute xn0 (with relu) via LDS: xn_lds[bn][ch], pitch 260 ----
  float* xn_lds = reinterpret_cast<float*>(bbuf);
#pragma unroll
  for (int m = 0; m < 4; ++m) {
    int mt = wv * 4 + m;
#pragma unroll
    for (int nt = 0; nt < 2; ++nt) {
      int bn = nt * 16 + colx;
      if (bn < 24) {
        f32x4 v = acc[m][nt];
        float4 w4 = make_float4(fmaxf(v[0], 0.0f), fmaxf(v[1], 0.0f),
                                fmaxf(v[2], 0.0f), fmaxf(v[3], 0.0f));
        *reinterpret_cast<float4*>(&xn_lds[bn * 260 + mt * 16 + g * 4]) = w4;
      }
    }
  }
  __syncthreads();

  // ---- phase 2 register layout: lane owns channels c0..c0+3 of its wave's batch ----
  const int c0 = lane * 4;
  float xn[4][6], xo[4][6];
#pragma unroll
  for (int n = 0; n < 6; ++n) {
    float4 t = *reinterpret_cast<const float4*>(&xn_lds[(wv * 6 + n) * 260 + c0]);
    xn[0][n] = t.x; xn[1][n] = t.y; xn[2][n] = t.z; xn[3][n] = t.w;
    xo[0][n] = t.x; xo[1][n] = t.y; xo[2][n] = t.z; xo[3][n] = t.w;
  }

  const float alpha = alphap[0];
  const float h = hp[0];
  const float beta = 1.0f / (1.0f + __expf(-alpha));
  const float al = (1.0f - beta) / h;
  const float be = beta / (h * h);
  const float invd = 1.0f / (be + al);
  const float cA = (2.0f * be + al) * invd;
  const float cB = -be * invd;

  const int PI[NPAIR] = {0,0,0,0,0,1,1,1,1,2,2,2,3,3,4};
  const int PJ[NPAIR] = {1,2,3,4,5,2,3,4,5,3,4,5,4,5,5};

#pragma unroll 1
  for (int it = 0; it < 4; ++it) {
    float D[NPAIR];
#pragma unroll
    for (int p = 0; p < NPAIR; ++p) D[p] = 0.0f;
#pragma unroll
    for (int p = 0; p < NPAIR; ++p) {
      const int i = PI[p], j = PJ[p];
#pragma unroll
      for (int k = 0; k < 4; ++k) {
        float df = xn[k][i] - xn[k][j];
        D[p] = fmaf(df, df, D[p]);
      }
    }
#pragma unroll
    for (int s = 32; s >= 1; s >>= 1)
#pragma unroll
      for (int p = 0; p < NPAIR; ++p) D[p] += __shfl_xor(D[p], s, 64);

    float sumD = 0.0f;
#pragma unroll
    for (int p = 0; p < NPAIR; ++p) sumD += D[p];
    float mean = sumD * (2.0f / 36.0f);
    float sc = 0.0f;
#pragma unroll
    for (int p = 0; p < NPAIR; ++p) {
      float dm = D[p] - mean;
      sc = fmaf(dm, dm, sc);
    }
    float var = (2.0f * sc + 6.0f * mean * mean) * (1.0f / 35.0f);
    float rstd = rsqrtf(var);

    float w[NPAIR];
#pragma unroll
    for (int p = 0; p < NPAIR; ++p) w[p] = __expf(-2.0f * D[p] * rstd);

    float dxn[4][6];
#pragma unroll
    for (int k = 0; k < 4; ++k)
#pragma unroll
      for (int n = 0; n < 6; ++n) dxn[k][n] = 0.0f;

#pragma unroll
    for (int p = 0; p < NPAIR; ++p) {
      const int i = PI[p], j = PJ[p];
      const float wp = w[p];
#pragma unroll
      for (int k = 0; k < 4; ++k) {
        float gg = wp * (xn[k][j] - xn[k][i]);
        float ax = fminf(fabsf(gg) * 64.0f, 511.0f);
        int ii = (int)ax;
        float fr = ax - (float)ii;
        float2 tt = Tt2[ii];
        float d = fmaf(fr, tt.y, tt.x);
        d = copysignf(d, gg);
        float wd = wp * d;
        dxn[k][j] += wd;
        dxn[k][i] -= wd;
      }
    }

#pragma unroll
    for (int k = 0; k < 4; ++k)
#pragma unroll
      for (int n = 0; n < 6; ++n) {
        float nv = cA * xn[k][n] + cB * xo[k][n] - invd * dxn[k][n];
        xo[k][n] = xn[k][n];
        xn[k][n] = nv;
      }
  }

  // ---- phase 3: out_b[n][o] = sum_c KNc[o,c]*xn[c,n] ----
  float po[6][6];
#pragma unroll
  for (int n = 0; n < 6; ++n)
#pragma unroll
    for (int o = 0; o < 6; ++o) po[n][o] = 0.0f;
#pragma unroll
  for (int k = 0; k < 4; ++k)
#pragma unroll
    for (int o = 0; o < 6; ++o) {
      float kv = KNc[(size_t)o * CDIM + c0 + k];
#pragma unroll
      for (int n = 0; n < 6; ++n) po[n][o] = fmaf(kv, xn[k][n], po[n][o]);
    }
#pragma unroll
  for (int s = 32; s >= 1; s >>= 1)
#pragma unroll
    for (int n = 0; n < 6; ++n)
#pragma unroll
      for (int o = 0; o < 6; ++o) po[n][o] += __shfl_xor(po[n][o], s, 64);

  if (lane == 0) {
#pragma unroll
    for (int n = 0; n < 6; ++n)
#pragma unroll
      for (int o = 0; o < 6; ++o) Ms[wv][n * 6 + o] = po[n][o];
  }
  __syncthreads();   // Ms ready; all waves done with xn_lds -> bbuf reusable as staging

  // ---- stage all outputs into LDS in exact output order ----
  float* stg   = reinterpret_cast<float*>(bbuf);        // [4][1536] xn, 24576 B
  float* wstg  = stg + 6144;                            // [4][72]   Wl,  1152 B
  float* o0stg = wstg + 288;                            // [4][6]    out0,  96 B

  {
    float4* sp = reinterpret_cast<float4*>(stg) + wv * 384 + lane * 6;
    sp[0] = make_float4(xn[0][0], xn[0][1], xn[0][2], xn[0][3]);
    sp[1] = make_float4(xn[0][4], xn[0][5], xn[1][0], xn[1][1]);
    sp[2] = make_float4(xn[1][2], xn[1][3], xn[1][4], xn[1][5]);
    sp[3] = make_float4(xn[2][0], xn[2][1], xn[2][2], xn[2][3]);
    sp[4] = make_float4(xn[2][4], xn[2][5], xn[3][0], xn[3][1]);
    sp[5] = make_float4(xn[3][2], xn[3][3], xn[3][4], xn[3][5]);
  }

  if (lane < 6) o0stg[wv * 6 + lane] = Ms[wv][lane];

  {
    const int p = lane;
    float Dp = 0.0f;
    int o1 = 0, o2 = 0;
    if (p < 36) {
      o1 = p / 6; o2 = p % 6;
#pragma unroll
      for (int n = 0; n < 6; ++n) {
        float diff = Ms[wv][n * 6 + o1] - Ms[wv][n * 6 + o2];
        Dp = fmaf(diff, diff, Dp);
      }
    }
    float sD = Dp;
#pragma unroll
    for (int s = 32; s >= 1; s >>= 1) sD += __shfl_xor(sD, s, 64);
    float meanl = sD * (1.0f / 36.0f);
    float c2 = 0.0f;
    if (p < 36) { float dm = Dp - meanl; c2 = dm * dm; }
    float sc2 = c2;
#pragma unroll
    for (int s = 32; s >= 1; s >>= 1) sc2 += __shfl_xor(sc2, s, 64);
    float rstdl = rsqrtf(sc2 * (1.0f / 35.0f));
    if (p < 36) {
      float wnew = __expf(-2.0f * Dp * rstdl) - ((o1 == o2) ? 10.0f : 0.0f);
      wstg[wv * 72 + p * 2]     = (o1 == o2) ? 1.0f : 0.0f;
      wstg[wv * 72 + p * 2 + 1] = wnew;
    }
  }
  __syncthreads();

  // ---- coalesced block-contiguous output copies ----
  {
    const float4* s4 = reinterpret_cast<const float4*>(stg);
    float4* dst4 = reinterpret_cast<float4*>(out + XN_OFF) + (size_t)b0 * 384;
#pragma unroll
    for (int i = 0; i < 6; ++i)
      dst4[threadIdx.x + 256 * i] = s4[threadIdx.x + 256 * i];
  }
  if (threadIdx.x < 72) {
    float4* wdst = reinterpret_cast<float4*>(out + WL_OFF + (size_t)b0 * 72);
    wdst[threadIdx.x] = reinterpret_cast<const float4*>(wstg)[threadIdx.x];
  }
  if (threadIdx.x < 6) {
    float4* odst = reinterpret_cast<float4*>(out + (size_t)b0 * 6);
    odst[threadIdx.x] = reinterpret_cast<const float4*>(o0stg)[threadIdx.x];
  }
}

// ---- fallback (ws too small): R2 VALU kernel with direct K1 reads ----
__global__ __launch_bounds__(256) void pdegcn_fallback(
    const float* __restrict__ x,
    const float* __restrict__ K1,
    const float* __restrict__ KNc,
    const float* __restrict__ alphap,
    const float* __restrict__ hp,
    float* __restrict__ out)
{
  __shared__ float Tt[1025];
  __shared__ float Ms[4][36];

  const int wv = threadIdx.x >> 6;
  const int lane = threadIdx.x & 63;
  const int b = blockIdx.x * 4 + wv;
  const int c0 = lane * 4;

  for (int i = threadIdx.x; i < 1025; i += 256) {
    float v = (float)i * (1.0f / 128.0f);
#pragma unroll
    for (int t = 0; t < 5; ++t) {
      float e = __expf(2.0f * v);
      v = 1.0f - __fdividef(2.0f, e + 1.0f);
    }
    Tt[i] = v;
  }
  __syncthreads();

  const float alpha = alphap[0];
  const float h = hp[0];
  const float beta = 1.0f / (1.0f + __expf(-alpha));
  const float al = (1.0f - beta) / h;
  const float be = beta / (h * h);
  const float invd = 1.0f / (be + al);
  const float cA = (2.0f * be + al) * invd;
  const float cB = -be * invd;

  const float* xb = x + (size_t)b * (NNODES * CDIM);

  float acc[4][6];
#pragma unroll
  for (int k = 0; k < 4; ++k)
#pragma unroll
    for (int n = 0; n < 6; ++n) acc[k][n] = 0.0f;

#pragma unroll 1
  for (int c = 0; c < CDIM; c += 4) {
    float xr[6][4];
#pragma unroll
    for (int n = 0; n < 6; ++n) {
      float4 v = *reinterpret_cast<const float4*>(xb + n * CDIM + c);
      xr[n][0] = v.x; xr[n][1] = v.y; xr[n][2] = v.z; xr[n][3] = v.w;
    }
#pragma unroll
    for (int cc = 0; cc < 4; ++cc) {
      float kk[4];
#pragma unroll
      for (int k = 0; k < 4; ++k) kk[k] = K1[(size_t)(c0 + k) * CDIM + c + cc];
#pragma unroll
      for (int k = 0; k < 4; ++k)
#pragma unroll
        for (int n = 0; n < 6; ++n)
          acc[k][n] = fmaf(kk[k], xr[n][cc], acc[k][n]);
    }
  }

  float xn[4][6], xo[4][6];
#pragma unroll
  for (int k = 0; k < 4; ++k)
#pragma unroll
    for (int n = 0; n < 6; ++n) {
      float v = fmaxf(acc[k][n], 0.0f);
      xn[k][n] = v; xo[k][n] = v;
    }

  const int PI[NPAIR] = {0,0,0,0,0,1,1,1,1,2,2,2,3,3,4};
  const int PJ[NPAIR] = {1,2,3,4,5,2,3,4,5,3,4,5,4,5,5};

#pragma unroll 1
  for (int it = 0; it < 4; ++it) {
    float D[NPAIR];
#pragma unroll
    for (int p = 0; p < NPAIR; ++p) D[p] = 0.0f;
#pragma unroll
    for (int p = 0; p < NPAIR; ++p) {
      const int i = PI[p], j = PJ[p];
#pragma unroll
      for (int k = 0; k < 4; ++k) {
        float df = xn[k][i] - xn[k][j];
        D[p] = fmaf(df, df, D[p]);
      }
    }
#pragma unroll
    for (int s = 32; s >= 1; s >>= 1)
#pragma unroll
      for (int p = 0; p < NPAIR; ++p) D[p] += __shfl_xor(D[p], s, 64);

    float sumD = 0.0f;
#pragma unroll
    for (int p = 0; p < NPAIR; ++p) sumD += D[p];
    float mean = sumD * (2.0f / 36.0f);
    float sc = 0.0f;
#pragma unroll
    for (int p = 0; p < NPAIR; ++p) {
      float dm = D[p] - mean;
      sc = fmaf(dm, dm, sc);
    }
    float var = (2.0f * sc + 6.0f * mean * mean) * (1.0f / 35.0f);
    float rstd = rsqrtf(var);

    float w[NPAIR];
#pragma unroll
    for (int p = 0; p < NPAIR; ++p) w[p] = __expf(-2.0f * D[p] * rstd);

    float dxn[4][6];
#pragma unroll
    for (int k = 0; k < 4; ++k)
#pragma unroll
      for (int n = 0; n < 6; ++n) dxn[k][n] = 0.0f;

#pragma unroll
    for (int p = 0; p < NPAIR; ++p) {
      const int i = PI[p], j = PJ[p];
      const float wp = w[p];
#pragma unroll
      for (int k = 0; k < 4; ++k) {
        float gg = wp * (xn[k][j] - xn[k][i]);
        float ax = fminf(fabsf(gg) * 128.0f, 1023.0f);
        int ii = (int)ax;
        float fr = ax - (float)ii;
        float ta = Tt[ii];
        float tb = Tt[ii + 1];
        float d = fmaf(fr, tb - ta, ta);
        d = copysignf(d, gg);
        float wd = wp * d;
        dxn[k][j] += wd;
        dxn[k][i] -= wd;
      }
    }

#pragma unroll
    for (int k = 0; k < 4; ++k)
#pragma unroll
      for (int n = 0; n < 6; ++n) {
        float nv = cA * xn[k][n] + cB * xo[k][n] - invd * dxn[k][n];
        xo[k][n] = xn[k][n];
        xn[k][n] = nv;
      }
  }

  float po[6][6];
#pragma unroll
  for (int n = 0; n < 6; ++n)
#pragma unroll
    for (int o = 0; o < 6; ++o) po[n][o] = 0.0f;
#pragma unroll
  for (int k = 0; k < 4; ++k)
#pragma unroll
    for (int o = 0; o < 6; ++o) {
      float kv = KNc[(size_t)o * CDIM + c0 + k];
#pragma unroll
      for (int n = 0; n < 6; ++n) po[n][o] = fmaf(kv, xn[k][n], po[n][o]);
    }
#pragma unroll
  for (int s = 32; s >= 1; s >>= 1)
#pragma unroll
    for (int n = 0; n < 6; ++n)
#pragma unroll
      for (int o = 0; o < 6; ++o) po[n][o] += __shfl_xor(po[n][o], s, 64);

  if (lane == 0) {
#pragma unroll
    for (int n = 0; n < 6; ++n)
#pragma unroll
      for (int o = 0; o < 6; ++o) Ms[wv][n * 6 + o] = po[n][o];
  }
  __syncthreads();

  if (lane < 6) out[(size_t)b * 6 + lane] = Ms[wv][lane];

  {
    float4* d4 = reinterpret_cast<float4*>(out + XN_OFF + (size_t)b * (CDIM * NNODES) + (size_t)c0 * NNODES);
    d4[0] = make_float4(xn[0][0], xn[0][1], xn[0][2], xn[0][3]);
    d4[1] = make_float4(xn[0][4], xn[0][5], xn[1][0], xn[1][1]);
    d4[2] = make_float4(xn[1][2], xn[1][3], xn[1][4], xn[1][5]);
    d4[3] = make_float4(xn[2][0], xn[2][1], xn[2][2], xn[2][3]);
    d4[4] = make_float4(xn[2][4], xn[2][5], xn[3][0], xn[3][1]);
    d4[5] = make_float4(xn[3][2], xn[3][3], xn[3][4], xn[3][5]);
  }

  {
    const int p = lane;
    float Dp = 0.0f;
    int o1 = 0, o2 = 0;
    if (p < 36) {
      o1 = p / 6; o2 = p % 6;
#pragma unroll
      for (int n = 0; n < 6; ++n) {
        float diff = Ms[wv][n * 6 + o1] - Ms[wv][n * 6 + o2];
        Dp = fmaf(diff, diff, Dp);
      }
    }
    float sD = Dp;
#pragma unroll
    for (int s = 32; s >= 1; s >>= 1) sD += __shfl_xor(sD, s, 64);
    float meanl = sD * (1.0f / 36.0f);
    float c2 = 0.0f;
    if (p < 36) { float dm = Dp - meanl; c2 = dm * dm; }
    float sc2 = c2;
#pragma unroll
    for (int s = 32; s >= 1; s >>= 1) sc2 += __shfl_xor(sc2, s, 64);
    float rstdl = rsqrtf(sc2 * (1.0f / 35.0f));
    if (p < 36) {
      float wnew = __expf(-2.0f * Dp * rstdl) - ((o1 == o2) ? 10.0f : 0.0f);
      size_t base = WL_OFF + ((size_t)b * 36 + p) * 2;
      out[base] = (o1 == o2) ? 1.0f : 0.0f;
      out[base + 1] = wnew;
    }
  }
}

extern "C" void kernel_launch(void* const* d_in, const int* in_sizes, int n_in,
                              void* d_out, int out_size, void* d_ws, size_t ws_size,
                              hipStream_t stream) {
  (void)in_sizes; (void)n_in; (void)out_size;
  const float* x     = (const float*)d_in[0];
  const float* K1    = (const float*)d_in[1];
  const float* KNc   = (const float*)d_in[2];
  const float* alpha = (const float*)d_in[3];
  const float* h     = (const float*)d_in[4];
  float* out = (float*)d_out;

  if (ws_size >= 262144) {
    uint4* Ah = (uint4*)d_ws;
    uint4* Al = Ah + 8192;
    split_k1<<<32, 256, 0, stream>>>(K1, Ah, Al);
    pdegcn_mfma<<<BTOT / 4, 256, 0, stream>>>(x, Ah, Al, KNc, alpha, h, out);
  } else {
    pdegcn_fallback<<<BTOT / 4, 256, 0, stream>>>(x, K1, KNc, alpha, h, out);
  }
}

// Round 6
// 115.329 us; speedup vs baseline: 3.8965x; 1.1105x over previous
//
#include <hip/hip_runtime.h>
#include <math.h>

#define NNODES 6
#define CDIM 256
#define NPAIR 15
#define BTOT 8192

// offsets in d_out (floats)
#define XN_OFF   49152ULL          // 8192*6
#define WL_OFF   12632064ULL       // 49152 + 8192*256*6

typedef __attribute__((ext_vector_type(8))) short short8v;   // 8 bf16 = 4 VGPR
typedef __attribute__((ext_vector_type(4))) float f32x4;

static __device__ __forceinline__ unsigned bf16_rne(float f) {
  unsigned u = __float_as_uint(f);
  return (u + 0x7FFFu + ((u >> 16) & 1u)) >> 16;
}

static __device__ __forceinline__ float tanh1(float v) {
  float e = __expf(2.0f * v);
  return 1.0f - __fdividef(2.0f, e + 1.0f);
}

// ---- wave-64 all-reduce sum: xor1/2/4/8 via DPP (VALU), xor16 via ds_swizzle,
// xor32 via shfl. 2 LDS-pipe ops instead of 6. ----
template <int CTRL>
static __device__ __forceinline__ float dpp_add(float v) {
  int s = __builtin_bit_cast(int, v);
  int t = __builtin_amdgcn_update_dpp(s, s, CTRL, 0xF, 0xF, false);
  return v + __builtin_bit_cast(float, t);
}
static __device__ __forceinline__ float wave_sum(float v) {
  v = dpp_add<0xB1>(v);    // quad_perm [1,0,3,2]  : xor 1
  v = dpp_add<0x4E>(v);    // quad_perm [2,3,0,1]  : xor 2
  v = dpp_add<0x141>(v);   // row_half_mirror      : xor 4
  v = dpp_add<0x140>(v);   // row_mirror           : xor 8
  int s = __builtin_bit_cast(int, v);
  int t = __builtin_amdgcn_ds_swizzle(s, 0x401F);   // xor 16 (within 32-lane rows)
  v += __builtin_bit_cast(float, t);
  v += __shfl_xor(v, 32, 64);                       // xor 32
  return v;
}

// ---- prep: split K1 (fp32) into bf16 hi/lo, laid out in MFMA A-fragment order ----
__global__ void split_k1(const float* __restrict__ K1,
                         uint4* __restrict__ Ah, uint4* __restrict__ Al) {
  int t = blockIdx.x * 256 + threadIdx.x;    // 8192 threads
  int o = t >> 5, c8 = t & 31;
  const float* src = K1 + (size_t)o * 256 + c8 * 8;
  unsigned hi[8], lo[8];
#pragma unroll
  for (int j = 0; j < 8; ++j) {
    float f = src[j];
    unsigned hr = bf16_rne(f);
    float hf = __uint_as_float(hr << 16);
    lo[j] = bf16_rne(f - hf);
    hi[j] = hr;
  }
  int s = c8 >> 2, ko = c8 & 3, mt = o >> 4, row = o & 15;
  int idx16 = ((s * 16 + mt) * 4 + ko) * 16 + row;
  Ah[idx16] = make_uint4(hi[0] | (hi[1] << 16), hi[2] | (hi[3] << 16),
                         hi[4] | (hi[5] << 16), hi[6] | (hi[7] << 16));
  Al[idx16] = make_uint4(lo[0] | (lo[1] << 16), lo[2] | (lo[3] << 16),
                         lo[4] | (lo[5] << 16), lo[6] | (lo[7] << 16));
}

// ---- main kernel: 4 batches per block, 1 batch per wave for phases 2/3 ----
// launch_bounds(256,2): 256-reg unified budget -> no scratch spill (R4/R5 lesson).
// LDS compacted to 27.2 KB so LDS no longer caps occupancy below the VGPR cap.
__global__ __launch_bounds__(256, 2) void pdegcn_mfma(
    const float* __restrict__ x,
    const uint4* __restrict__ Ahg,
    const uint4* __restrict__ Alg,
    const float* __restrict__ KNc,
    const float* __restrict__ alphap,
    const float* __restrict__ hp,
    float* __restrict__ out)
{
  // bbuf (24576 B): phase1 = x as bf16 hi/lo B-fragments, 24 cols (compact);
  // phase2 = xn_lds[24][256] fp32 (XOR-swizzled); epilogue = xn output staging.
  __shared__ unsigned short bbuf[12288];
  __shared__ float2 Tt2[256];    // tanh5 table: (value, delta), x in [0,8), step 1/32
  __shared__ float Ms[4][36];

  const int wv = threadIdx.x >> 6;
  const int lane = threadIdx.x & 63;
  const int b0 = blockIdx.x * 4;
  const int b = b0 + wv;

  // ---- build tanh5 table ----
  {
    int i = threadIdx.x;
    if (i < 256) {
      float v0 = (float)i * (1.0f / 32.0f);
      float v1 = (float)(i + 1) * (1.0f / 32.0f);
#pragma unroll
      for (int t = 0; t < 5; ++t) { v0 = tanh1(v0); v1 = tanh1(v1); }
      Tt2[i] = make_float2(v0, v1 - v0);
    }
  }

  // ---- stage x -> bf16 hi/lo B-fragments in LDS (24 cols, XOR-swizzled col) ----
  {
    const float4* x4 = reinterpret_cast<const float4*>(x) + (size_t)b0 * 384;
#pragma unroll
    for (int i = 0; i < 6; ++i) {
      int idx = threadIdx.x + 256 * i;          // 1536 float4s: p = idx>>6, c4 = idx&63
      int p = idx >> 6, c4 = idx & 63;
      float4 v = x4[idx];
      float f[4] = {v.x, v.y, v.z, v.w};
      unsigned hh[4], ll[4];
#pragma unroll
      for (int j = 0; j < 4; ++j) {
        unsigned hr = bf16_rne(f[j]);
        float hf = __uint_as_float(hr << 16);
        ll[j] = bf16_rne(f[j] - hf);
        hh[j] = hr;
      }
      int ko = c4 >> 1, jb = (c4 & 1) * 4;
      int colS = p ^ (ko & 7);
      int hw = (ko * 24 + colS) * 8 + jb;
      *reinterpret_cast<uint2*>(&bbuf[hw]) =
          make_uint2(hh[0] | (hh[1] << 16), hh[2] | (hh[3] << 16));
      *reinterpret_cast<uint2*>(&bbuf[6144 + hw]) =
          make_uint2(ll[0] | (ll[1] << 16), ll[2] | (ll[3] << 16));
    }
  }
  __syncthreads();

  // ---- phase 1: MFMA  C[o, bn] = sum_c K1[o,c] * x[bn, c]  (M=256, N=24, K=256) ----
  f32x4 acc[4][2];
#pragma unroll
  for (int m = 0; m < 4; ++m)
#pragma unroll
    for (int nt = 0; nt < 2; ++nt)
      acc[m][nt] = (f32x4){0.0f, 0.0f, 0.0f, 0.0f};

  const int g = lane >> 4, colx = lane & 15;
  const short8v* Ah8 = reinterpret_cast<const short8v*>(Ahg);
  const short8v* Al8 = reinterpret_cast<const short8v*>(Alg);
  const char* bb = reinterpret_cast<const char*>(bbuf);

#pragma unroll 2
  for (int s = 0; s < 8; ++s) {
    int ko = s * 4 + g;
    int q = ko & 7;
    short8v bh[2], bl[2];
#pragma unroll
    for (int nt = 0; nt < 2; ++nt) {
      // cols 24..31 (nt=1, colx>=8) read past the compact array: harmless
      // finite garbage -> garbage lands only in discarded C cols 24..31.
      int off16 = ko * 24 + ((nt * 16 + colx) ^ q);
      bh[nt] = *reinterpret_cast<const short8v*>(bb + off16 * 16);
      bl[nt] = *reinterpret_cast<const short8v*>(bb + 12288 + off16 * 16);
    }
#pragma unroll
    for (int m = 0; m < 4; ++m) {
      int mt = wv * 4 + m;
      int ai = (s * 16 + mt) * 64 + lane;
      short8v a_h = Ah8[ai];
      short8v a_l = Al8[ai];
#pragma unroll
      for (int nt = 0; nt < 2; ++nt) {
        acc[m][nt] = __builtin_amdgcn_mfma_f32_16x16x32_bf16(a_h, bh[nt], acc[m][nt], 0, 0, 0);
        acc[m][nt] = __builtin_amdgcn_mfma_f32_16x16x32_bf16(a_h, bl[nt], acc[m][nt], 0, 0, 0);
        acc[m][nt] = __builtin_amdgcn_mfma_f32_16x16x32_bf16(a_l, bh[nt], acc[m][nt], 0, 0, 0);
      }
    }
  }
  __syncthreads();   // all waves done reading bbuf; reuse as xn_lds

  // ---- redistribute xn0 (with relu) via LDS: xn_lds[bn][256], XOR-swizzled ----
  float* xn_lds = reinterpret_cast<float*>(bbuf);
#pragma unroll
  for (int m = 0; m < 4; ++m) {
    int mt = wv * 4 + m;
#pragma unroll
    for (int nt = 0; nt < 2; ++nt) {
      int bn = nt * 16 + colx;
      if (bn < 24) {
        f32x4 v = acc[m][nt];
        float4 w4 = make_float4(fmaxf(v[0], 0.0f), fmaxf(v[1], 0.0f),
                                fmaxf(v[2], 0.0f), fmaxf(v[3], 0.0f));
        int cidx = (mt * 16 + g * 4) ^ ((bn & 7) << 2);
        *reinterpret_cast<float4*>(&xn_lds[bn * 256 + cidx]) = w4;
      }
    }
  }
  __syncthreads();

  // ---- phase 2 register layout: lane owns channels c0..c0+3 of its wave's batch ----
  const int c0 = lane * 4;
  float xn[4][6], xo[4][6];
#pragma unroll
  for (int n = 0; n < 6; ++n) {
    int row = wv * 6 + n;
    float4 t = *reinterpret_cast<const float4*>(&xn_lds[row * 256 + (c0 ^ ((row & 7) << 2))]);
    xn[0][n] = t.x; xn[1][n] = t.y; xn[2][n] = t.z; xn[3][n] = t.w;
    xo[0][n] = t.x; xo[1][n] = t.y; xo[2][n] = t.z; xo[3][n] = t.w;
  }

  const float alpha = alphap[0];
  const float h = hp[0];
  const float beta = 1.0f / (1.0f + __expf(-alpha));
  const float al = (1.0f - beta) / h;
  const float be = beta / (h * h);
  const float invd = 1.0f / (be + al);
  const float cA = (2.0f * be + al) * invd;
  const float cB = -be * invd;

  const int PI[NPAIR] = {0,0,0,0,0,1,1,1,1,2,2,2,3,3,4};
  const int PJ[NPAIR] = {1,2,3,4,5,2,3,4,5,3,4,5,4,5,5};

#pragma unroll 1
  for (int it = 0; it < 4; ++it) {
    float D[NPAIR];
#pragma unroll
    for (int p = 0; p < NPAIR; ++p) D[p] = 0.0f;
#pragma unroll
    for (int p = 0; p < NPAIR; ++p) {
      const int i = PI[p], j = PJ[p];
#pragma unroll
      for (int k = 0; k < 4; ++k) {
        float df = xn[k][i] - xn[k][j];
        D[p] = fmaf(df, df, D[p]);
      }
    }
#pragma unroll
    for (int p = 0; p < NPAIR; ++p) D[p] = wave_sum(D[p]);

    float sumD = 0.0f;
#pragma unroll
    for (int p = 0; p < NPAIR; ++p) sumD += D[p];
    float mean = sumD * (2.0f / 36.0f);
    float sc = 0.0f;
#pragma unroll
    for (int p = 0; p < NPAIR; ++p) {
      float dm = D[p] - mean;
      sc = fmaf(dm, dm, sc);
    }
    float var = (2.0f * sc + 6.0f * mean * mean) * (1.0f / 35.0f);
    float rstd = rsqrtf(var);
    float rs2 = -2.885390082f * rstd;   // -2*log2(e)*rstd

    float w[NPAIR];
#pragma unroll
    for (int p = 0; p < NPAIR; ++p) w[p] = exp2f(D[p] * rs2);

    float dxn[4][6];
#pragma unroll
    for (int k = 0; k < 4; ++k)
#pragma unroll
      for (int n = 0; n < 6; ++n) dxn[k][n] = 0.0f;

#pragma unroll
    for (int p = 0; p < NPAIR; ++p) {
      const int i = PI[p], j = PJ[p];
      const float wp = w[p];
#pragma unroll
      for (int k = 0; k < 4; ++k) {
        float gg = wp * (xn[k][j] - xn[k][i]);
        float ax = fminf(fabsf(gg) * 32.0f, 255.0f);
        int ii = (int)ax;
        float fr = ax - (float)ii;
        float2 tt = Tt2[ii];
        float d = fmaf(fr, tt.y, tt.x);
        d = copysignf(d, gg);
        float wd = wp * d;
        dxn[k][j] += wd;
        dxn[k][i] -= wd;
      }
    }

#pragma unroll
    for (int k = 0; k < 4; ++k)
#pragma unroll
      for (int n = 0; n < 6; ++n) {
        float nv = cA * xn[k][n] + cB * xo[k][n] - invd * dxn[k][n];
        xo[k][n] = xn[k][n];
        xn[k][n] = nv;
      }
  }

  // ---- phase 3: out_b[n][o] = sum_c KNc[o,c]*xn[c,n] ----
  float po[6][6];
#pragma unroll
  for (int n = 0; n < 6; ++n)
#pragma unroll
    for (int o = 0; o < 6; ++o) po[n][o] = 0.0f;
#pragma unroll
  for (int k = 0; k < 4; ++k)
#pragma unroll
    for (int o = 0; o < 6; ++o) {
      float kv = KNc[(size_t)o * CDIM + c0 + k];
#pragma unroll
      for (int n = 0; n < 6; ++n) po[n][o] = fmaf(kv, xn[k][n], po[n][o]);
    }
#pragma unroll
  for (int n = 0; n < 6; ++n)
#pragma unroll
    for (int o = 0; o < 6; ++o) po[n][o] = wave_sum(po[n][o]);

  if (lane == 0) {
#pragma unroll
    for (int n = 0; n < 6; ++n)
#pragma unroll
      for (int o = 0; o < 6; ++o) Ms[wv][n * 6 + o] = po[n][o];
  }
  __syncthreads();   // Ms ready; all waves done with xn_lds; Tt2 dead after loop

  // ---- stage all outputs into LDS in exact output order ----
  float* stg   = reinterpret_cast<float*>(bbuf);    // [4][1536] xn, 24576 B (full bbuf)
  float* wstg  = reinterpret_cast<float*>(Tt2);     // [4][72]   Wl, 1152 B (table dead)
  float* o0stg = wstg + 288;                        // [4][6]    out0, 96 B

  {
    float4* sp = reinterpret_cast<float4*>(stg) + wv * 384 + lane * 6;
    sp[0] = make_float4(xn[0][0], xn[0][1], xn[0][2], xn[0][3]);
    sp[1] = make_float4(xn[0][4], xn[0][5], xn[1][0], xn[1][1]);
    sp[2] = make_float4(xn[1][2], xn[1][3], xn[1][4], xn[1][5]);
    sp[3] = make_float4(xn[2][0], xn[2][1], xn[2][2], xn[2][3]);
    sp[4] = make_float4(xn[2][4], xn[2][5], xn[3][0], xn[3][1]);
    sp[5] = make_float4(xn[3][2], xn[3][3], xn[3][4], xn[3][5]);
  }

  if (lane < 6) o0stg[wv * 6 + lane] = Ms[wv][lane];

  {
    const int p = lane;
    float Dp = 0.0f;
    int o1 = 0, o2 = 0;
    if (p < 36) {
      o1 = p / 6; o2 = p % 6;
#pragma unroll
      for (int n = 0; n < 6; ++n) {
        float diff = Ms[wv][n * 6 + o1] - Ms[wv][n * 6 + o2];
        Dp = fmaf(diff, diff, Dp);
      }
    }
    float sD = wave_sum(Dp);
    float meanl = sD * (1.0f / 36.0f);
    float c2 = 0.0f;
    if (p < 36) { float dm = Dp - meanl; c2 = dm * dm; }
    float sc2 = wave_sum(c2);
    float rstdl = rsqrtf(sc2 * (1.0f / 35.0f));
    if (p < 36) {
      float wnew = __expf(-2.0f * Dp * rstdl) - ((o1 == o2) ? 10.0f : 0.0f);
      wstg[wv * 72 + p * 2]     = (o1 == o2) ? 1.0f : 0.0f;
      wstg[wv * 72 + p * 2 + 1] = wnew;
    }
  }
  __syncthreads();

  // ---- coalesced block-contiguous output copies ----
  {
    const float4* s4 = reinterpret_cast<const float4*>(stg);
    float4* dst4 = reinterpret_cast<float4*>(out + XN_OFF) + (size_t)b0 * 384;
#pragma unroll
    for (int i = 0; i < 6; ++i)
      dst4[threadIdx.x + 256 * i] = s4[threadIdx.x + 256 * i];
  }
  if (threadIdx.x < 72) {
    float4* wdst = reinterpret_cast<float4*>(out + WL_OFF + (size_t)b0 * 72);
    wdst[threadIdx.x] = reinterpret_cast<const float4*>(wstg)[threadIdx.x];
  }
  if (threadIdx.x < 6) {
    float4* odst = reinterpret_cast<float4*>(out + (size_t)b0 * 6);
    odst[threadIdx.x] = reinterpret_cast<const float4*>(o0stg)[threadIdx.x];
  }
}

// ---- fallback (ws too small): VALU kernel with direct K1 reads ----
__global__ __launch_bounds__(256) void pdegcn_fallback(
    const float* __restrict__ x,
    const float* __restrict__ K1,
    const float* __restrict__ KNc,
    const float* __restrict__ alphap,
    const float* __restrict__ hp,
    float* __restrict__ out)
{
  __shared__ float Tt[1025];
  __shared__ float Ms[4][36];

  const int wv = threadIdx.x >> 6;
  const int lane = threadIdx.x & 63;
  const int b = blockIdx.x * 4 + wv;
  const int c0 = lane * 4;

  for (int i = threadIdx.x; i < 1025; i += 256) {
    float v = (float)i * (1.0f / 128.0f);
#pragma unroll
    for (int t = 0; t < 5; ++t) {
      float e = __expf(2.0f * v);
      v = 1.0f - __fdividef(2.0f, e + 1.0f);
    }
    Tt[i] = v;
  }
  __syncthreads();

  const float alpha = alphap[0];
  const float h = hp[0];
  const float beta = 1.0f / (1.0f + __expf(-alpha));
  const float al = (1.0f - beta) / h;
  const float be = beta / (h * h);
  const float invd = 1.0f / (be + al);
  const float cA = (2.0f * be + al) * invd;
  const float cB = -be * invd;

  const float* xb = x + (size_t)b * (NNODES * CDIM);

  float acc[4][6];
#pragma unroll
  for (int k = 0; k < 4; ++k)
#pragma unroll
    for (int n = 0; n < 6; ++n) acc[k][n] = 0.0f;

#pragma unroll 1
  for (int c = 0; c < CDIM; c += 4) {
    float xr[6][4];
#pragma unroll
    for (int n = 0; n < 6; ++n) {
      float4 v = *reinterpret_cast<const float4*>(xb + n * CDIM + c);
      xr[n][0] = v.x; xr[n][1] = v.y; xr[n][2] = v.z; xr[n][3] = v.w;
    }
#pragma unroll
    for (int cc = 0; cc < 4; ++cc) {
      float kk[4];
#pragma unroll
      for (int k = 0; k < 4; ++k) kk[k] = K1[(size_t)(c0 + k) * CDIM + c + cc];
#pragma unroll
      for (int k = 0; k < 4; ++k)
#pragma unroll
        for (int n = 0; n < 6; ++n)
          acc[k][n] = fmaf(kk[k], xr[n][cc], acc[k][n]);
    }
  }

  float xn[4][6], xo[4][6];
#pragma unroll
  for (int k = 0; k < 4; ++k)
#pragma unroll
    for (int n = 0; n < 6; ++n) {
      float v = fmaxf(acc[k][n], 0.0f);
      xn[k][n] = v; xo[k][n] = v;
    }

  const int PI[NPAIR] = {0,0,0,0,0,1,1,1,1,2,2,2,3,3,4};
  const int PJ[NPAIR] = {1,2,3,4,5,2,3,4,5,3,4,5,4,5,5};

#pragma unroll 1
  for (int it = 0; it < 4; ++it) {
    float D[NPAIR];
#pragma unroll
    for (int p = 0; p < NPAIR; ++p) D[p] = 0.0f;
#pragma unroll
    for (int p = 0; p < NPAIR; ++p) {
      const int i = PI[p], j = PJ[p];
#pragma unroll
      for (int k = 0; k < 4; ++k) {
        float df = xn[k][i] - xn[k][j];
        D[p] = fmaf(df, df, D[p]);
      }
    }
#pragma unroll
    for (int s = 32; s >= 1; s >>= 1)
#pragma unroll
      for (int p = 0; p < NPAIR; ++p) D[p] += __shfl_xor(D[p], s, 64);

    float sumD = 0.0f;
#pragma unroll
    for (int p = 0; p < NPAIR; ++p) sumD += D[p];
    float mean = sumD * (2.0f / 36.0f);
    float sc = 0.0f;
#pragma unroll
    for (int p = 0; p < NPAIR; ++p) {
      float dm = D[p] - mean;
      sc = fmaf(dm, dm, sc);
    }
    float var = (2.0f * sc + 6.0f * mean * mean) * (1.0f / 35.0f);
    float rstd = rsqrtf(var);

    float w[NPAIR];
#pragma unroll
    for (int p = 0; p < NPAIR; ++p) w[p] = __expf(-2.0f * D[p] * rstd);

    float dxn[4][6];
#pragma unroll
    for (int k = 0; k < 4; ++k)
#pragma unroll
      for (int n = 0; n < 6; ++n) dxn[k][n] = 0.0f;

#pragma unroll
    for (int p = 0; p < NPAIR; ++p) {
      const int i = PI[p], j = PJ[p];
      const float wp = w[p];
#pragma unroll
      for (int k = 0; k < 4; ++k) {
        float gg = wp * (xn[k][j] - xn[k][i]);
        float ax = fminf(fabsf(gg) * 128.0f, 1023.0f);
        int ii = (int)ax;
        float fr = ax - (float)ii;
        float ta = Tt[ii];
        float tb = Tt[ii + 1];
        float d = fmaf(fr, tb - ta, ta);
        d = copysignf(d, gg);
        float wd = wp * d;
        dxn[k][j] += wd;
        dxn[k][i] -= wd;
      }
    }

#pragma unroll
    for (int k = 0; k < 4; ++k)
#pragma unroll
      for (int n = 0; n < 6; ++n) {
        float nv = cA * xn[k][n] + cB * xo[k][n] - invd * dxn[k][n];
        xo[k][n] = xn[k][n];
        xn[k][n] = nv;
      }
  }

  float po[6][6];
#pragma unroll
  for (int n = 0; n < 6; ++n)
#pragma unroll
    for (int o = 0; o < 6; ++o) po[n][o] = 0.0f;
#pragma unroll
  for (int k = 0; k < 4; ++k)
#pragma unroll
    for (int o = 0; o < 6; ++o) {
      float kv = KNc[(size_t)o * CDIM + c0 + k];
#pragma unroll
      for (int n = 0; n < 6; ++n) po[n][o] = fmaf(kv, xn[k][n], po[n][o]);
    }
#pragma unroll
  for (int s = 32; s >= 1; s >>= 1)
#pragma unroll
    for (int n = 0; n < 6; ++n)
#pragma unroll
      for (int o = 0; o < 6; ++o) po[n][o] += __shfl_xor(po[n][o], s, 64);

  if (lane == 0) {
#pragma unroll
    for (int n = 0; n < 6; ++n)
#pragma unroll
      for (int o = 0; o < 6; ++o) Ms[wv][n * 6 + o] = po[n][o];
  }
  __syncthreads();

  if (lane < 6) out[(size_t)b * 6 + lane] = Ms[wv][lane];

  {
    float4* d4 = reinterpret_cast<float4*>(out + XN_OFF + (size_t)b * (CDIM * NNODES) + (size_t)c0 * NNODES);
    d4[0] = make_float4(xn[0][0], xn[0][1], xn[0][2], xn[0][3]);
    d4[1] = make_float4(xn[0][4], xn[0][5], xn[1][0], xn[1][1]);
    d4[2] = make_float4(xn[1][2], xn[1][3], xn[1][4], xn[1][5]);
    d4[3] = make_float4(xn[2][0], xn[2][1], xn[2][2], xn[2][3]);
    d4[4] = make_float4(xn[2][4], xn[2][5], xn[3][0], xn[3][1]);
    d4[5] = make_float4(xn[3][2], xn[3][3], xn[3][4], xn[3][5]);
  }

  {
    const int p = lane;
    float Dp = 0.0f;
    int o1 = 0, o2 = 0;
    if (p < 36) {
      o1 = p / 6; o2 = p % 6;
#pragma unroll
      for (int n = 0; n < 6; ++n) {
        float diff = Ms[wv][n * 6 + o1] - Ms[wv][n * 6 + o2];
        Dp = fmaf(diff, diff, Dp);
      }
    }
    float sD = Dp;
#pragma unroll
    for (int s = 32; s >= 1; s >>= 1) sD += __shfl_xor(sD, s, 64);
    float meanl = sD * (1.0f / 36.0f);
    float c2 = 0.0f;
    if (p < 36) { float dm = Dp - meanl; c2 = dm * dm; }
    float sc2 = c2;
#pragma unroll
    for (int s = 32; s >= 1; s >>= 1) sc2 += __shfl_xor(sc2, s, 64);
    float rstdl = rsqrtf(sc2 * (1.0f / 35.0f));
    if (p < 36) {
      float wnew = __expf(-2.0f * Dp * rstdl) - ((o1 == o2) ? 10.0f : 0.0f);
      size_t base = WL_OFF + ((size_t)b * 36 + p) * 2;
      out[base] = (o1 == o2) ? 1.0f : 0.0f;
      out[base + 1] = wnew;
    }
  }
}

extern "C" void kernel_launch(void* const* d_in, const int* in_sizes, int n_in,
                              void* d_out, int out_size, void* d_ws, size_t ws_size,
                              hipStream_t stream) {
  (void)in_sizes; (void)n_in; (void)out_size;
  const float* x     = (const float*)d_in[0];
  const float* K1    = (const float*)d_in[1];
  const float* KNc   = (const float*)d_in[2];
  const float* alpha = (const float*)d_in[3];
  const float* h     = (const float*)d_in[4];
  float* out = (float*)d_out;

  if (ws_size >= 262144) {
    uint4* Ah = (uint4*)d_ws;
    uint4* Al = Ah + 8192;
    split_k1<<<32, 256, 0, stream>>>(K1, Ah, Al);
    pdegcn_mfma<<<BTOT / 4, 256, 0, stream>>>(x, Ah, Al, KNc, alpha, h, out);
  } else {
    pdegcn_fallback<<<BTOT / 4, 256, 0, stream>>>(x, K1, KNc, alpha, h, out);
  }
}